// Round 6
// baseline (366.229 us; speedup 1.0000x reference)
//
#include <hip/hip_runtime.h>
#include <hip/hip_bf16.h>

#define NN 50000
#define NE 800000
#define HD 128
#define SCAN_CHUNK 1024
#define SCAN_BLOCKS ((NN + SCAN_CHUNK - 1) / SCAN_CHUNK)  // 49

typedef __attribute__((ext_vector_type(8))) short s16x8;
typedef __attribute__((ext_vector_type(4))) float f32x4;

static __device__ __forceinline__ unsigned short f2bf(float f) {
    unsigned int u = __float_as_uint(f);
    u = (u + 0x7FFFu + ((u >> 16) & 1u)) >> 16;
    return (unsigned short)u;
}
static __device__ __forceinline__ float bf2f(unsigned short h) {
    return __uint_as_float(((unsigned int)h) << 16);
}
static __device__ __forceinline__ unsigned int f2bf2(float lo, float hi) {
    __hip_bfloat162 h = __float22bfloat162_rn(make_float2(lo, hi));
    return *reinterpret_cast<unsigned int*>(&h);
}

// wave-level LDS fence: drain this wave's LDS ops, block compiler reordering.
#define WFENCE() do { asm volatile("s_waitcnt lgkmcnt(0)" ::: "memory"); \
                      __builtin_amdgcn_sched_barrier(0); } while (0)

// ---------------------------------------------------------------------------
// prep: Wpc = pw2 @ mw1[256:288,:]  (32x128), bc = pb2 @ mw1[256:288,:] + mb1
// ---------------------------------------------------------------------------
__global__ void prep_kernel(const float* __restrict__ pw2, const float* __restrict__ pb2,
                            const float* __restrict__ mw1, const float* __restrict__ mb1,
                            float* __restrict__ Wpc, float* __restrict__ bc)
{
    int tid = threadIdx.x;
    for (int idx = tid; idx < 32 * 128; idx += 256) {
        int j = idx >> 7, k = idx & 127;
        float s = 0.f;
        #pragma unroll 8
        for (int i = 0; i < 32; ++i) s += pw2[j * 32 + i] * mw1[(256 + i) * 128 + k];
        Wpc[idx] = s;
    }
    if (tid < 128) {
        float s = mb1[tid];
        #pragma unroll 8
        for (int i = 0; i < 32; ++i) s += pb2[i] * mw1[(256 + i) * 128 + tid];
        bc[tid] = s;
    }
}

// ---------------------------------------------------------------------------
// hist: count edges per destination col (2 edges/thread, vector loads)
// ---------------------------------------------------------------------------
__global__ void hist_kernel(const int* __restrict__ ei, int* __restrict__ cnt)
{
    __shared__ int sIdx64;
    if (threadIdx.x == 0) {
        int z = 1;
        for (int k = 0; k < 16; ++k) if (ei[2 * k + 1] != 0) z = 0;
        sIdx64 = z;
    }
    __syncthreads();
    int g = blockIdx.x * 256 + threadIdx.x;
    if (g >= NE / 2) return;
    int e0 = g * 2;
    int c0, c1;
    if (sIdx64) { int4 q = *(const int4*)&ei[2 * NE + 2 * e0]; c0 = q.x; c1 = q.z; }
    else        { int2 q = *(const int2*)&ei[NE + e0];         c0 = q.x; c1 = q.y; }
    atomicAdd(&cnt[c0], 1);
    atomicAdd(&cnt[c1], 1);
}

// ---------------------------------------------------------------------------
// parallel exclusive scan: per-chunk scan -> cursor, chunk totals -> bsum
// ---------------------------------------------------------------------------
__global__ void scan1_kernel(const int* __restrict__ cnt, int* __restrict__ cursor,
                             int* __restrict__ bsum)
{
    __shared__ int tot[256];
    int b = blockIdx.x, t = threadIdx.x;
    int i0 = b * SCAN_CHUNK + t * 4;
    int v[4];
    #pragma unroll
    for (int k = 0; k < 4; ++k) v[k] = (i0 + k < NN) ? cnt[i0 + k] : 0;
    tot[t] = v[0] + v[1] + v[2] + v[3];
    __syncthreads();
    if (t == 0) {
        int run = 0;
        for (int i = 0; i < 256; ++i) { int x = tot[i]; tot[i] = run; run += x; }
        bsum[b] = run;
    }
    __syncthreads();
    int p = tot[t];
    #pragma unroll
    for (int k = 0; k < 4; ++k) {
        if (i0 + k < NN) cursor[i0 + k] = p;
        p += v[k];
    }
}

__global__ void scan2_kernel(int* __restrict__ bsum)
{
    if (threadIdx.x == 0) {
        int run = 0;
        for (int i = 0; i < SCAN_BLOCKS; ++i) { int x = bsum[i]; bsum[i] = run; run += x; }
    }
}

__global__ void scan3_kernel(int* __restrict__ cursor, const int* __restrict__ bsum)
{
    int b = blockIdx.x, t = threadIdx.x;
    int carry = bsum[b];
    int i0 = b * SCAN_CHUNK + t * 4;
    #pragma unroll
    for (int k = 0; k < 4; ++k)
        if (i0 + k < NN) cursor[i0 + k] += carry;
}

// ---------------------------------------------------------------------------
// scatter: place (r,c) pairs at sorted-by-c positions (2 edges/thread)
// ---------------------------------------------------------------------------
__global__ void scatter_kernel(const int* __restrict__ ei,
                               int* __restrict__ cursor, int2* __restrict__ sRC)
{
    __shared__ int sIdx64;
    if (threadIdx.x == 0) {
        int z = 1;
        for (int k = 0; k < 16; ++k) if (ei[2 * k + 1] != 0) z = 0;
        sIdx64 = z;
    }
    __syncthreads();
    int g = blockIdx.x * 256 + threadIdx.x;
    if (g >= NE / 2) return;
    int e0 = g * 2;
    int r0, r1, c0, c1;
    if (sIdx64) {
        int4 qr = *(const int4*)&ei[2 * e0];           r0 = qr.x; r1 = qr.z;
        int4 qc = *(const int4*)&ei[2 * NE + 2 * e0];  c0 = qc.x; c1 = qc.z;
    } else {
        int2 qr = *(const int2*)&ei[e0];       r0 = qr.x; r1 = qr.y;
        int2 qc = *(const int2*)&ei[NE + e0];  c0 = qc.x; c1 = qc.y;
    }
    int p0 = atomicAdd(&cursor[c0], 1);
    sRC[p0] = make_int2(r0, c0);
    int p1 = atomicAdd(&cursor[c1], 1);
    sRC[p1] = make_int2(r1, c1);
}

// ---------------------------------------------------------------------------
// stage 1: xa = bf16(x @ mw1[0:128,:]), xb = bf16(x @ mw1[128:256,:])
// coalesced bf16 stores via per-wave LDS staging.
// ---------------------------------------------------------------------------
__global__ __launch_bounds__(256, 2) void node_pre_kernel(
    const float* __restrict__ x, const float* __restrict__ mw1,
    unsigned short* __restrict__ xa, unsigned short* __restrict__ xb)
{
    __shared__ __align__(16) unsigned short sB[256 * 136];   // [c<256][k<128]
    __shared__ __align__(16) unsigned short sSt[4][16 * 64];

    int tid = threadIdx.x;
    for (int idx = tid; idx < 256 * 128; idx += 256) {
        int c = idx & 255, k = idx >> 8;
        float v = (c < 128) ? mw1[k * 128 + c] : mw1[(128 + k) * 128 + (c - 128)];
        sB[c * 136 + k] = f2bf(v);
    }
    __syncthreads();

    int lane = tid & 63, wv = tid >> 6;
    int r16 = lane & 15, g4 = lane >> 4;
    unsigned short* st = sSt[wv];
    const int NT = NN / 16;  // 3125

    for (int t = blockIdx.x * 4 + wv; t < NT; t += gridDim.x * 4) {
        int r0 = t * 16;
        int row = r0 + r16;
        s16x8 a[4];
        #pragma unroll
        for (int ks = 0; ks < 4; ++ks) {
            const float* p = &x[(size_t)row * HD + ks * 32 + g4 * 8];
            float4 v0 = *(const float4*)p;
            float4 v1 = *(const float4*)(p + 4);
            union { s16x8 v; unsigned int u[4]; } av;
            av.u[0] = f2bf2(v0.x, v0.y); av.u[1] = f2bf2(v0.z, v0.w);
            av.u[2] = f2bf2(v1.x, v1.y); av.u[3] = f2bf2(v1.z, v1.w);
            a[ks] = av.v;
        }
        #pragma unroll
        for (int grp = 0; grp < 4; ++grp) {
            #pragma unroll
            for (int tc2 = 0; tc2 < 4; ++tc2) {
                int tc = grp * 4 + tc2;
                int col = tc * 16 + r16;
                f32x4 acc = {0.f, 0.f, 0.f, 0.f};
                #pragma unroll
                for (int ks = 0; ks < 4; ++ks) {
                    s16x8 b = *(const s16x8*)&sB[col * 136 + ks * 32 + g4 * 8];
                    acc = __builtin_amdgcn_mfma_f32_16x16x32_bf16(a[ks], b, acc, 0, 0, 0);
                }
                #pragma unroll
                for (int j = 0; j < 4; ++j)
                    st[(g4 * 4 + j) * 64 + tc2 * 16 + r16] = f2bf(acc[j]);
            }
            WFENCE();
            unsigned short* dst = (grp < 2) ? xa : xb;
            int ch = (grp & 1) * 64;
            #pragma unroll
            for (int i = 0; i < 2; ++i) {
                int idx = i * 512 + lane * 8;
                int rr = idx >> 6, cc = idx & 63;
                *(s16x8*)&dst[(size_t)(r0 + rr) * HD + ch + cc] = *(const s16x8*)&st[idx];
            }
            WFENCE();
        }
    }
}

// ---------------------------------------------------------------------------
// stage 2 (edges, SORTED by col): 512-thread blocks (8 waves share one mw2
// LDS tile -> 16 waves/CU), wave-private 16-edge tiles, strided lockstep
// sweep, shfl-derived gather meta, b32-packed segmented reduce.
// ---------------------------------------------------------------------------
__global__ __launch_bounds__(512, 4) void edge_kernel(
    const float* __restrict__ pos, const int2* __restrict__ sRC,
    const float* __restrict__ pw1, const float* __restrict__ pb1,
    const float* __restrict__ mw2, const float* __restrict__ mb2,
    const unsigned short* __restrict__ xa, const unsigned short* __restrict__ xb,
    const float* __restrict__ Wpc, const float* __restrict__ bc,
    float* __restrict__ agg)
{
    __shared__ __align__(16) unsigned short sB[128 * 136];     // mw2 [c][k]
    __shared__ __align__(16) unsigned short sT[8][16 * 136];   // per-wave stg/HR/msg
    __shared__ int sECs[8][16];

    int tid = threadIdx.x;
    for (int idx = tid; idx < 128 * 128; idx += 512) {
        int c = idx & 127, k = idx >> 7;
        sB[c * 136 + k] = f2bf(mw2[k * 128 + c]);
    }
    __syncthreads();  // only block barrier

    int lane = tid & 63, wv = tid >> 6;
    int r16 = lane & 15, g4 = lane >> 4;
    unsigned short* stg = sT[wv];
    int* secw = sECs[wv];

    s16x8 wr[8];
    #pragma unroll
    for (int tc = 0; tc < 8; ++tc) {
        s16x8 w;
        #pragma unroll
        for (int i = 0; i < 8; ++i)
            w[i] = (short)f2bf(Wpc[(g4 * 8 + i) * 128 + tc * 16 + r16]);
        wr[tc] = w;
    }
    float pw10[8], pw11[8], pw12[8], pb1r[8], bcg[8], mb2r[8];
    #pragma unroll
    for (int i = 0; i < 8; ++i) {
        int k = g4 * 8 + i;
        pw10[i] = pw1[k]; pw11[i] = pw1[32 + k]; pw12[i] = pw1[64 + k];
        pb1r[i] = pb1[k];
        bcg[i] = bc[r16 * 8 + i];
    }
    #pragma unroll
    for (int tc = 0; tc < 8; ++tc) mb2r[tc] = mb2[tc * 16 + r16];

    const int NW = gridDim.x * 8;
    const int NT = NE / 16;  // 50000
    int gw = blockIdx.x * 8 + wv;
    if (gw >= NT) return;

    // prologue: meta + gathers for first tile
    int2 rc = sRC[gw * 16 + r16];
    float dp0 = pos[rc.x * 3 + 0] - pos[rc.y * 3 + 0];
    float dp1 = pos[rc.x * 3 + 1] - pos[rc.y * 3 + 1];
    float dp2 = pos[rc.x * 3 + 2] - pos[rc.y * 3 + 2];
    s16x8 ga[4], gb[4];
    #pragma unroll
    for (int s = 0; s < 4; ++s) {
        int gx = __shfl(rc.x, s * 4 + g4, 64);
        int gy = __shfl(rc.y, s * 4 + g4, 64);
        ga[s] = *(const s16x8*)&xa[(size_t)gx * HD + r16 * 8];
        gb[s] = *(const s16x8*)&xb[(size_t)gy * HD + r16 * 8];
    }

    for (int t = gw; t < NT; t += NW) {
        int tn = t + NW;
        bool hn = tn < NT;

        // ---- 1. staging: bf16(xa[row]+xb[col]+bc) -> stg
        #pragma unroll
        for (int s = 0; s < 4; ++s) {
            union { s16x8 v; unsigned int u[4]; } o;
            #pragma unroll
            for (int i2 = 0; i2 < 4; ++i2) {
                float v0 = bf2f((unsigned short)ga[s][2 * i2]) +
                           bf2f((unsigned short)gb[s][2 * i2]) + bcg[2 * i2];
                float v1 = bf2f((unsigned short)ga[s][2 * i2 + 1]) +
                           bf2f((unsigned short)gb[s][2 * i2 + 1]) + bcg[2 * i2 + 1];
                o.u[i2] = f2bf2(v0, v1);
            }
            *(s16x8*)&stg[(s * 4 + g4) * 136 + r16 * 8] = o.v;
        }
        if (lane < 16) secw[lane] = rc.y;
        WFENCE();

        // ---- 2. next-tile meta
        int2 rcN;
        if (hn) rcN = sRC[tn * 16 + r16];

        // ---- 3. pos-MLP layer1 in A-frag layout
        union { s16x8 v; unsigned int u[4]; } apf;
        #pragma unroll
        for (int i2 = 0; i2 < 4; ++i2) {
            int i = 2 * i2;
            float v0 = fmaf(dp0, pw10[i], fmaf(dp1, pw11[i], fmaf(dp2, pw12[i], pb1r[i])));
            float v1 = fmaf(dp0, pw10[i+1], fmaf(dp1, pw11[i+1], fmaf(dp2, pw12[i+1], pb1r[i+1])));
            apf.u[i2] = f2bf2(fmaxf(v0, 0.f), fmaxf(v1, 0.f));
        }

        // ---- 4. GEMM1: h1 = pf@Wpc + stg ; relu -> same buffer (per-lane RMW)
        #pragma unroll
        for (int tc = 0; tc < 8; ++tc) {
            f32x4 z = {0.f, 0.f, 0.f, 0.f};
            f32x4 a1 = __builtin_amdgcn_mfma_f32_16x16x32_bf16(apf.v, wr[tc], z, 0, 0, 0);
            #pragma unroll
            for (int j = 0; j < 4; ++j) {
                int e = g4 * 4 + j, col = tc * 16 + r16;
                float v = a1[j] + bf2f(stg[e * 136 + col]);
                stg[e * 136 + col] = f2bf(fmaxf(v, 0.f));
            }
        }
        WFENCE();

        // ---- 5. A-frags of GEMM2 from HR
        s16x8 a2[4];
        #pragma unroll
        for (int ks = 0; ks < 4; ++ks)
            a2[ks] = *(const s16x8*)&stg[r16 * 136 + ks * 32 + g4 * 8];
        WFENCE();  // a2 in regs before step 7 overwrites

        // ---- 6. next-tile pos diffs
        float dp0N = 0.f, dp1N = 0.f, dp2N = 0.f;
        if (hn) {
            dp0N = pos[rcN.x * 3 + 0] - pos[rcN.y * 3 + 0];
            dp1N = pos[rcN.x * 3 + 1] - pos[rcN.y * 3 + 1];
            dp2N = pos[rcN.x * 3 + 2] - pos[rcN.y * 3 + 2];
        }

        // ---- 7. GEMM2: msg = HR @ mw2 + mb2 -> stg (overlay)
        #pragma unroll
        for (int tc = 0; tc < 8; ++tc) {
            f32x4 acc = {mb2r[tc], mb2r[tc], mb2r[tc], mb2r[tc]};
            #pragma unroll
            for (int ks = 0; ks < 4; ++ks) {
                s16x8 b = *(const s16x8*)&sB[(tc * 16 + r16) * 136 + ks * 32 + g4 * 8];
                acc = __builtin_amdgcn_mfma_f32_16x16x32_bf16(a2[ks], b, acc, 0, 0, 0);
            }
            #pragma unroll
            for (int j = 0; j < 4; ++j)
                stg[(g4 * 4 + j) * 136 + tc * 16 + r16] = f2bf(acc[j]);
        }
        WFENCE();

        // ---- 8. next-tile gathers (hide under segred)
        if (hn) {
            #pragma unroll
            for (int s = 0; s < 4; ++s) {
                int gx = __shfl(rcN.x, s * 4 + g4, 64);
                int gy = __shfl(rcN.y, s * 4 + g4, 64);
                ga[s] = *(const s16x8*)&xa[(size_t)gx * HD + r16 * 8];
                gb[s] = *(const s16x8*)&xb[(size_t)gy * HD + r16 * 8];
            }
        }

        // ---- 9. segmented reduce over sorted cols -> atomics (b32 packed)
        {
            int c0 = 2 * lane;  // col pair (c0, c0+1)
            int cur = secw[0];
            unsigned int pv = *(const unsigned int*)&stg[c0];
            float run0 = bf2f((unsigned short)(pv & 0xffff));
            float run1 = bf2f((unsigned short)(pv >> 16));
            #pragma unroll
            for (int e = 1; e < 16; ++e) {
                int c = secw[e];
                unsigned int qv = *(const unsigned int*)&stg[e * 136 + c0];
                float v0 = bf2f((unsigned short)(qv & 0xffff));
                float v1 = bf2f((unsigned short)(qv >> 16));
                if (c != cur) {  // wave-uniform
                    unsafeAtomicAdd(&agg[(size_t)cur * HD + c0], run0);
                    unsafeAtomicAdd(&agg[(size_t)cur * HD + c0 + 1], run1);
                    cur = c; run0 = v0; run1 = v1;
                } else { run0 += v0; run1 += v1; }
            }
            unsafeAtomicAdd(&agg[(size_t)cur * HD + c0], run0);
            unsafeAtomicAdd(&agg[(size_t)cur * HD + c0 + 1], run1);
        }
        WFENCE();

        rc = rcN; dp0 = dp0N; dp1 = dp1N; dp2 = dp2N;
    }
}

// ---------------------------------------------------------------------------
// stage 3a: tbuf = bf16(relu(x@uw1a + agg@uw1b + ub1)), coalesced stores
// ---------------------------------------------------------------------------
__global__ __launch_bounds__(256, 2) void upd1_kernel(
    const float* __restrict__ x, const float* __restrict__ agg,
    const float* __restrict__ uw1, const float* __restrict__ ub1,
    unsigned short* __restrict__ tbuf)
{
    __shared__ __align__(16) unsigned short sB1[128 * 264];
    __shared__ __align__(16) unsigned short sSt[4][16 * 64];

    int tid = threadIdx.x;
    for (int idx = tid; idx < 256 * 128; idx += 256) {
        int c = idx & 127, k = idx >> 7;
        sB1[c * 264 + k] = f2bf(uw1[k * 128 + c]);
    }
    __syncthreads();

    int lane = tid & 63, wv = tid >> 6;
    int r16 = lane & 15, g4 = lane >> 4;
    unsigned short* st = sSt[wv];
    float ub1r[8];
    #pragma unroll
    for (int tc = 0; tc < 8; ++tc) ub1r[tc] = ub1[tc * 16 + r16];

    const int NT = NN / 16;
    for (int t = blockIdx.x * 4 + wv; t < NT; t += gridDim.x * 4) {
        int r0 = t * 16;
        int row = r0 + r16;
        s16x8 a[8];
        #pragma unroll
        for (int ks = 0; ks < 8; ++ks) {
            const float* p = (ks < 4) ? &x[(size_t)row * HD + ks * 32 + g4 * 8]
                                      : &agg[(size_t)row * HD + (ks - 4) * 32 + g4 * 8];
            float4 v0 = *(const float4*)p;
            float4 v1 = *(const float4*)(p + 4);
            union { s16x8 v; unsigned int u[4]; } av;
            av.u[0] = f2bf2(v0.x, v0.y); av.u[1] = f2bf2(v0.z, v0.w);
            av.u[2] = f2bf2(v1.x, v1.y); av.u[3] = f2bf2(v1.z, v1.w);
            a[ks] = av.v;
        }
        #pragma unroll
        for (int half = 0; half < 2; ++half) {
            #pragma unroll
            for (int tc2 = 0; tc2 < 4; ++tc2) {
                int tc = half * 4 + tc2;
                int col = tc * 16 + r16;
                float bv = ub1r[tc];
                f32x4 acc = {bv, bv, bv, bv};
                #pragma unroll
                for (int ks = 0; ks < 8; ++ks) {
                    s16x8 b = *(const s16x8*)&sB1[col * 264 + ks * 32 + g4 * 8];
                    acc = __builtin_amdgcn_mfma_f32_16x16x32_bf16(a[ks], b, acc, 0, 0, 0);
                }
                #pragma unroll
                for (int j = 0; j < 4; ++j)
                    st[(g4 * 4 + j) * 64 + tc2 * 16 + r16] = f2bf(fmaxf(acc[j], 0.f));
            }
            WFENCE();
            #pragma unroll
            for (int i = 0; i < 2; ++i) {
                int idx = i * 512 + lane * 8;
                int rr = idx >> 6, cc = idx & 63;
                *(s16x8*)&tbuf[(size_t)(r0 + rr) * HD + half * 64 + cc] = *(const s16x8*)&st[idx];
            }
            WFENCE();
        }
    }
}

// ---------------------------------------------------------------------------
// stage 3b: out = tbuf @ uw2 + ub2
// ---------------------------------------------------------------------------
__global__ __launch_bounds__(256, 4) void upd2_kernel(
    const unsigned short* __restrict__ tbuf,
    const float* __restrict__ uw2, const float* __restrict__ ub2,
    float* __restrict__ out)
{
    __shared__ __align__(16) unsigned short sB2[128 * 136];

    int tid = threadIdx.x;
    for (int idx = tid; idx < 128 * 128; idx += 256) {
        int c = idx & 127, k = idx >> 7;
        sB2[c * 136 + k] = f2bf(uw2[k * 128 + c]);
    }
    __syncthreads();

    int lane = tid & 63, wv = tid >> 6;
    int r16 = lane & 15, g4 = lane >> 4;
    float ub2r[8];
    #pragma unroll
    for (int tc = 0; tc < 8; ++tc) ub2r[tc] = ub2[tc * 16 + r16];

    const int NT = NN / 16;
    for (int t = blockIdx.x * 4 + wv; t < NT; t += gridDim.x * 4) {
        int r0 = t * 16;
        s16x8 a[4];
        #pragma unroll
        for (int ks = 0; ks < 4; ++ks)
            a[ks] = *(const s16x8*)&tbuf[(size_t)(r0 + r16) * HD + ks * 32 + g4 * 8];
        #pragma unroll
        for (int tc = 0; tc < 8; ++tc) {
            int col = tc * 16 + r16;
            float bv = ub2r[tc];
            f32x4 acc = {bv, bv, bv, bv};
            #pragma unroll
            for (int ks = 0; ks < 4; ++ks) {
                s16x8 b = *(const s16x8*)&sB2[col * 136 + ks * 32 + g4 * 8];
                acc = __builtin_amdgcn_mfma_f32_16x16x32_bf16(a[ks], b, acc, 0, 0, 0);
            }
            #pragma unroll
            for (int j = 0; j < 4; ++j)
                out[(size_t)(r0 + g4 * 4 + j) * HD + col] = acc[j];
        }
    }
}

// ---------------------------------------------------------------------------
extern "C" void kernel_launch(void* const* d_in, const int* in_sizes, int n_in,
                              void* d_out, int out_size, void* d_ws, size_t ws_size,
                              hipStream_t stream)
{
    const float* x   = (const float*)d_in[0];
    const float* pos = (const float*)d_in[1];
    const int*   ei  = (const int*)d_in[2];
    const float* pw1 = (const float*)d_in[3];
    const float* pb1 = (const float*)d_in[4];
    const float* pw2 = (const float*)d_in[5];
    const float* pb2 = (const float*)d_in[6];
    const float* mw1 = (const float*)d_in[7];
    const float* mb1 = (const float*)d_in[8];
    const float* mw2 = (const float*)d_in[9];
    const float* mb2 = (const float*)d_in[10];
    const float* uw1 = (const float*)d_in[11];
    const float* ub1 = (const float*)d_in[12];
    const float* uw2 = (const float*)d_in[13];
    const float* ub2 = (const float*)d_in[14];
    float* out = (float*)d_out;

    char* ws = (char*)d_ws;
    float*          agg    = (float*)(ws);                      // 25,600,000 B
    unsigned short* xa     = (unsigned short*)(ws + 25600000);  // 12,800,000 B
    unsigned short* xb     = (unsigned short*)(ws + 38400000);  // 12,800,000 B
    float*          Wpc    = (float*)(ws + 51200000);           // 16,384 B
    float*          bcv    = (float*)(ws + 51216384);           // 512 B
    int*            cnt    = (int*)(ws + 51216896);             // 200,704 B
    int*            cursor = (int*)(ws + 51417600);             // 200,704 B
    int*            bsum   = (int*)(ws + 51618304);             // 256 B
    int2*           sRC    = (int2*)(ws + 51618560);            // 6,400,000 B

    unsigned short* tbuf = xa;  // xa dead after edge_kernel

    hipMemsetAsync(agg, 0, (size_t)NN * HD * sizeof(float), stream);
    hipMemsetAsync(cnt, 0, NN * sizeof(int), stream);
    hist_kernel<<<(NE / 2 + 255) / 256, 256, 0, stream>>>(ei, cnt);
    scan1_kernel<<<SCAN_BLOCKS, 256, 0, stream>>>(cnt, cursor, bsum);
    scan2_kernel<<<1, 64, 0, stream>>>(bsum);
    scan3_kernel<<<SCAN_BLOCKS, 256, 0, stream>>>(cursor, bsum);
    prep_kernel<<<1, 256, 0, stream>>>(pw2, pb2, mw1, mb1, Wpc, bcv);
    scatter_kernel<<<(NE / 2 + 255) / 256, 256, 0, stream>>>(ei, cursor, sRC);
    node_pre_kernel<<<512, 256, 0, stream>>>(x, mw1, xa, xb);
    edge_kernel<<<512, 512, 0, stream>>>(pos, sRC, pw1, pb1, mw2, mb2, xa, xb, Wpc, bcv, agg);
    upd1_kernel<<<512, 256, 0, stream>>>(x, agg, uw1, ub1, tbuf);
    upd2_kernel<<<768, 256, 0, stream>>>(tbuf, uw2, ub2, out);
}

// Round 7
// 315.470 us; speedup vs baseline: 1.1609x; 1.1609x over previous
//
#include <hip/hip_runtime.h>
#include <hip/hip_bf16.h>

#define NN 50000
#define NE 800000
#define HD 128
#define SCAN_CHUNK 1024
#define SCAN_BLOCKS ((NN + SCAN_CHUNK - 1) / SCAN_CHUNK)  // 49

typedef __attribute__((ext_vector_type(8))) short s16x8;
typedef __attribute__((ext_vector_type(4))) float f32x4;

static __device__ __forceinline__ unsigned short f2bf(float f) {
    unsigned int u = __float_as_uint(f);
    u = (u + 0x7FFFu + ((u >> 16) & 1u)) >> 16;
    return (unsigned short)u;
}
static __device__ __forceinline__ float bf2f(unsigned short h) {
    return __uint_as_float(((unsigned int)h) << 16);
}
static __device__ __forceinline__ unsigned int f2bf2(float lo, float hi) {
    __hip_bfloat162 h = __float22bfloat162_rn(make_float2(lo, hi));
    return *reinterpret_cast<unsigned int*>(&h);
}

// wave-level LDS fence: drain this wave's LDS ops, block compiler reordering.
#define WFENCE() do { asm volatile("s_waitcnt lgkmcnt(0)" ::: "memory"); \
                      __builtin_amdgcn_sched_barrier(0); } while (0)

// ---------------------------------------------------------------------------
// prep: Wpc = pw2 @ mw1[256:288,:]  (32x128), bc = pb2 @ mw1[256:288,:] + mb1
// ---------------------------------------------------------------------------
__global__ void prep_kernel(const float* __restrict__ pw2, const float* __restrict__ pb2,
                            const float* __restrict__ mw1, const float* __restrict__ mb1,
                            float* __restrict__ Wpc, float* __restrict__ bc)
{
    int tid = threadIdx.x;
    for (int idx = tid; idx < 32 * 128; idx += 256) {
        int j = idx >> 7, k = idx & 127;
        float s = 0.f;
        #pragma unroll 8
        for (int i = 0; i < 32; ++i) s += pw2[j * 32 + i] * mw1[(256 + i) * 128 + k];
        Wpc[idx] = s;
    }
    if (tid < 128) {
        float s = mb1[tid];
        #pragma unroll 8
        for (int i = 0; i < 32; ++i) s += pb2[i] * mw1[(256 + i) * 128 + tid];
        bc[tid] = s;
    }
}

// ---------------------------------------------------------------------------
// hist: count edges per destination col (2 edges/thread, vector loads)
// ---------------------------------------------------------------------------
__global__ void hist_kernel(const int* __restrict__ ei, int* __restrict__ cnt)
{
    __shared__ int sIdx64;
    if (threadIdx.x == 0) {
        int z = 1;
        for (int k = 0; k < 16; ++k) if (ei[2 * k + 1] != 0) z = 0;
        sIdx64 = z;
    }
    __syncthreads();
    int g = blockIdx.x * 256 + threadIdx.x;
    if (g >= NE / 2) return;
    int e0 = g * 2;
    int c0, c1;
    if (sIdx64) { int4 q = *(const int4*)&ei[2 * NE + 2 * e0]; c0 = q.x; c1 = q.z; }
    else        { int2 q = *(const int2*)&ei[NE + e0];         c0 = q.x; c1 = q.y; }
    atomicAdd(&cnt[c0], 1);
    atomicAdd(&cnt[c1], 1);
}

// ---------------------------------------------------------------------------
// parallel exclusive scan
// ---------------------------------------------------------------------------
__global__ void scan1_kernel(const int* __restrict__ cnt, int* __restrict__ cursor,
                             int* __restrict__ bsum)
{
    __shared__ int tot[256];
    int b = blockIdx.x, t = threadIdx.x;
    int i0 = b * SCAN_CHUNK + t * 4;
    int v[4];
    #pragma unroll
    for (int k = 0; k < 4; ++k) v[k] = (i0 + k < NN) ? cnt[i0 + k] : 0;
    tot[t] = v[0] + v[1] + v[2] + v[3];
    __syncthreads();
    if (t == 0) {
        int run = 0;
        for (int i = 0; i < 256; ++i) { int x = tot[i]; tot[i] = run; run += x; }
        bsum[b] = run;
    }
    __syncthreads();
    int p = tot[t];
    #pragma unroll
    for (int k = 0; k < 4; ++k) {
        if (i0 + k < NN) cursor[i0 + k] = p;
        p += v[k];
    }
}

__global__ void scan2_kernel(int* __restrict__ bsum)
{
    if (threadIdx.x == 0) {
        int run = 0;
        for (int i = 0; i < SCAN_BLOCKS; ++i) { int x = bsum[i]; bsum[i] = run; run += x; }
    }
}

__global__ void scan3_kernel(int* __restrict__ cursor, const int* __restrict__ bsum)
{
    int b = blockIdx.x, t = threadIdx.x;
    int carry = bsum[b];
    int i0 = b * SCAN_CHUNK + t * 4;
    #pragma unroll
    for (int k = 0; k < 4; ++k)
        if (i0 + k < NN) cursor[i0 + k] += carry;
}

// ---------------------------------------------------------------------------
// scatter: place (r,c) pairs at sorted-by-c positions (2 edges/thread)
// ---------------------------------------------------------------------------
__global__ void scatter_kernel(const int* __restrict__ ei,
                               int* __restrict__ cursor, int2* __restrict__ sRC)
{
    __shared__ int sIdx64;
    if (threadIdx.x == 0) {
        int z = 1;
        for (int k = 0; k < 16; ++k) if (ei[2 * k + 1] != 0) z = 0;
        sIdx64 = z;
    }
    __syncthreads();
    int g = blockIdx.x * 256 + threadIdx.x;
    if (g >= NE / 2) return;
    int e0 = g * 2;
    int r0, r1, c0, c1;
    if (sIdx64) {
        int4 qr = *(const int4*)&ei[2 * e0];           r0 = qr.x; r1 = qr.z;
        int4 qc = *(const int4*)&ei[2 * NE + 2 * e0];  c0 = qc.x; c1 = qc.z;
    } else {
        int2 qr = *(const int2*)&ei[e0];       r0 = qr.x; r1 = qr.y;
        int2 qc = *(const int2*)&ei[NE + e0];  c0 = qc.x; c1 = qc.y;
    }
    int p0 = atomicAdd(&cursor[c0], 1);
    sRC[p0] = make_int2(r0, c0);
    int p1 = atomicAdd(&cursor[c1], 1);
    sRC[p1] = make_int2(r1, c1);
}

// ---------------------------------------------------------------------------
// stage 1: xa = bf16(x @ mw1[0:128,:]), xb = bf16(x @ mw1[128:256,:])
// coalesced bf16 stores via per-wave LDS staging.
// ---------------------------------------------------------------------------
__global__ __launch_bounds__(256, 2) void node_pre_kernel(
    const float* __restrict__ x, const float* __restrict__ mw1,
    unsigned short* __restrict__ xa, unsigned short* __restrict__ xb)
{
    __shared__ __align__(16) unsigned short sB[256 * 136];   // [c<256][k<128]
    __shared__ __align__(16) unsigned short sSt[4][16 * 64];

    int tid = threadIdx.x;
    for (int idx = tid; idx < 256 * 128; idx += 256) {
        int c = idx & 255, k = idx >> 8;
        float v = (c < 128) ? mw1[k * 128 + c] : mw1[(128 + k) * 128 + (c - 128)];
        sB[c * 136 + k] = f2bf(v);
    }
    __syncthreads();

    int lane = tid & 63, wv = tid >> 6;
    int r16 = lane & 15, g4 = lane >> 4;
    unsigned short* st = sSt[wv];
    const int NT = NN / 16;  // 3125

    for (int t = blockIdx.x * 4 + wv; t < NT; t += gridDim.x * 4) {
        int r0 = t * 16;
        int row = r0 + r16;
        s16x8 a[4];
        #pragma unroll
        for (int ks = 0; ks < 4; ++ks) {
            const float* p = &x[(size_t)row * HD + ks * 32 + g4 * 8];
            float4 v0 = *(const float4*)p;
            float4 v1 = *(const float4*)(p + 4);
            union { s16x8 v; unsigned int u[4]; } av;
            av.u[0] = f2bf2(v0.x, v0.y); av.u[1] = f2bf2(v0.z, v0.w);
            av.u[2] = f2bf2(v1.x, v1.y); av.u[3] = f2bf2(v1.z, v1.w);
            a[ks] = av.v;
        }
        #pragma unroll
        for (int grp = 0; grp < 4; ++grp) {
            #pragma unroll
            for (int tc2 = 0; tc2 < 4; ++tc2) {
                int tc = grp * 4 + tc2;
                int col = tc * 16 + r16;
                f32x4 acc = {0.f, 0.f, 0.f, 0.f};
                #pragma unroll
                for (int ks = 0; ks < 4; ++ks) {
                    s16x8 b = *(const s16x8*)&sB[col * 136 + ks * 32 + g4 * 8];
                    acc = __builtin_amdgcn_mfma_f32_16x16x32_bf16(a[ks], b, acc, 0, 0, 0);
                }
                #pragma unroll
                for (int j = 0; j < 4; ++j)
                    st[(g4 * 4 + j) * 64 + tc2 * 16 + r16] = f2bf(acc[j]);
            }
            WFENCE();
            unsigned short* dst = (grp < 2) ? xa : xb;
            int ch = (grp & 1) * 64;
            #pragma unroll
            for (int i = 0; i < 2; ++i) {
                int idx = i * 512 + lane * 8;
                int rr = idx >> 6, cc = idx & 63;
                *(s16x8*)&dst[(size_t)(r0 + rr) * HD + ch + cc] = *(const s16x8*)&st[idx];
            }
            WFENCE();
        }
    }
}

// ---------------------------------------------------------------------------
// stage 2 (edges, SORTED by col): 256-thr blocks, lb(256,3) (no spill),
// grid 512 -> 2048 co-resident waves (tight lockstep L2 window).
// wave-private 16-edge tiles, merged LDS buffer, shfl meta, b32 segred.
// ---------------------------------------------------------------------------
__global__ __launch_bounds__(256, 3) void edge_kernel(
    const float* __restrict__ pos, const int2* __restrict__ sRC,
    const float* __restrict__ pw1, const float* __restrict__ pb1,
    const float* __restrict__ mw2, const float* __restrict__ mb2,
    const unsigned short* __restrict__ xa, const unsigned short* __restrict__ xb,
    const float* __restrict__ Wpc, const float* __restrict__ bc,
    float* __restrict__ agg)
{
    __shared__ __align__(16) unsigned short sB[128 * 136];     // mw2 [c][k]
    __shared__ __align__(16) unsigned short sT[4][16 * 136];   // per-wave stg/HR/msg
    __shared__ int sECs[4][16];

    int tid = threadIdx.x;
    for (int idx = tid; idx < 128 * 128; idx += 256) {
        int c = idx & 127, k = idx >> 7;
        sB[c * 136 + k] = f2bf(mw2[k * 128 + c]);
    }
    __syncthreads();  // only block barrier

    int lane = tid & 63, wv = tid >> 6;
    int r16 = lane & 15, g4 = lane >> 4;
    unsigned short* stg = sT[wv];
    int* secw = sECs[wv];

    s16x8 wr[8];
    #pragma unroll
    for (int tc = 0; tc < 8; ++tc) {
        s16x8 w;
        #pragma unroll
        for (int i = 0; i < 8; ++i)
            w[i] = (short)f2bf(Wpc[(g4 * 8 + i) * 128 + tc * 16 + r16]);
        wr[tc] = w;
    }
    float pw10[8], pw11[8], pw12[8], pb1r[8], bcg[8], mb2r[8];
    #pragma unroll
    for (int i = 0; i < 8; ++i) {
        int k = g4 * 8 + i;
        pw10[i] = pw1[k]; pw11[i] = pw1[32 + k]; pw12[i] = pw1[64 + k];
        pb1r[i] = pb1[k];
        bcg[i] = bc[r16 * 8 + i];
    }
    #pragma unroll
    for (int tc = 0; tc < 8; ++tc) mb2r[tc] = mb2[tc * 16 + r16];

    const int NW = gridDim.x * 4;
    const int NT = NE / 16;  // 50000
    int gw = blockIdx.x * 4 + wv;
    if (gw >= NT) return;

    // prologue: meta + gathers for first tile
    int2 rc = sRC[gw * 16 + r16];
    float dp0 = pos[rc.x * 3 + 0] - pos[rc.y * 3 + 0];
    float dp1 = pos[rc.x * 3 + 1] - pos[rc.y * 3 + 1];
    float dp2 = pos[rc.x * 3 + 2] - pos[rc.y * 3 + 2];
    s16x8 ga[4], gb[4];
    #pragma unroll
    for (int s = 0; s < 4; ++s) {
        int gx = __shfl(rc.x, s * 4 + g4, 64);
        int gy = __shfl(rc.y, s * 4 + g4, 64);
        ga[s] = *(const s16x8*)&xa[(size_t)gx * HD + r16 * 8];
        gb[s] = *(const s16x8*)&xb[(size_t)gy * HD + r16 * 8];
    }

    for (int t = gw; t < NT; t += NW) {
        int tn = t + NW;
        bool hn = tn < NT;

        // ---- 1. staging: bf16(xa[row]+xb[col]+bc) -> stg
        #pragma unroll
        for (int s = 0; s < 4; ++s) {
            union { s16x8 v; unsigned int u[4]; } o;
            #pragma unroll
            for (int i2 = 0; i2 < 4; ++i2) {
                float v0 = bf2f((unsigned short)ga[s][2 * i2]) +
                           bf2f((unsigned short)gb[s][2 * i2]) + bcg[2 * i2];
                float v1 = bf2f((unsigned short)ga[s][2 * i2 + 1]) +
                           bf2f((unsigned short)gb[s][2 * i2 + 1]) + bcg[2 * i2 + 1];
                o.u[i2] = f2bf2(v0, v1);
            }
            *(s16x8*)&stg[(s * 4 + g4) * 136 + r16 * 8] = o.v;
        }
        if (lane < 16) secw[lane] = rc.y;
        WFENCE();

        // ---- 2. next-tile meta
        int2 rcN;
        if (hn) rcN = sRC[tn * 16 + r16];

        // ---- 3. pos-MLP layer1 in A-frag layout
        union { s16x8 v; unsigned int u[4]; } apf;
        #pragma unroll
        for (int i2 = 0; i2 < 4; ++i2) {
            int i = 2 * i2;
            float v0 = fmaf(dp0, pw10[i], fmaf(dp1, pw11[i], fmaf(dp2, pw12[i], pb1r[i])));
            float v1 = fmaf(dp0, pw10[i+1], fmaf(dp1, pw11[i+1], fmaf(dp2, pw12[i+1], pb1r[i+1])));
            apf.u[i2] = f2bf2(fmaxf(v0, 0.f), fmaxf(v1, 0.f));
        }

        // ---- 4. GEMM1: h1 = pf@Wpc + stg ; relu -> same buffer (per-lane RMW)
        #pragma unroll
        for (int tc = 0; tc < 8; ++tc) {
            f32x4 z = {0.f, 0.f, 0.f, 0.f};
            f32x4 a1 = __builtin_amdgcn_mfma_f32_16x16x32_bf16(apf.v, wr[tc], z, 0, 0, 0);
            #pragma unroll
            for (int j = 0; j < 4; ++j) {
                int e = g4 * 4 + j, col = tc * 16 + r16;
                float v = a1[j] + bf2f(stg[e * 136 + col]);
                stg[e * 136 + col] = f2bf(fmaxf(v, 0.f));
            }
        }
        WFENCE();

        // ---- 5. A-frags of GEMM2 from HR
        s16x8 a2[4];
        #pragma unroll
        for (int ks = 0; ks < 4; ++ks)
            a2[ks] = *(const s16x8*)&stg[r16 * 136 + ks * 32 + g4 * 8];
        WFENCE();  // a2 in regs before step 7 overwrites

        // ---- 6. next-tile pos diffs
        float dp0N = 0.f, dp1N = 0.f, dp2N = 0.f;
        if (hn) {
            dp0N = pos[rcN.x * 3 + 0] - pos[rcN.y * 3 + 0];
            dp1N = pos[rcN.x * 3 + 1] - pos[rcN.y * 3 + 1];
            dp2N = pos[rcN.x * 3 + 2] - pos[rcN.y * 3 + 2];
        }

        // ---- 7. GEMM2: msg = HR @ mw2 + mb2 -> stg (overlay)
        #pragma unroll
        for (int tc = 0; tc < 8; ++tc) {
            f32x4 acc = {mb2r[tc], mb2r[tc], mb2r[tc], mb2r[tc]};
            #pragma unroll
            for (int ks = 0; ks < 4; ++ks) {
                s16x8 b = *(const s16x8*)&sB[(tc * 16 + r16) * 136 + ks * 32 + g4 * 8];
                acc = __builtin_amdgcn_mfma_f32_16x16x32_bf16(a2[ks], b, acc, 0, 0, 0);
            }
            #pragma unroll
            for (int j = 0; j < 4; ++j)
                stg[(g4 * 4 + j) * 136 + tc * 16 + r16] = f2bf(acc[j]);
        }
        WFENCE();

        // ---- 8. next-tile gathers (hide under segred)
        if (hn) {
            #pragma unroll
            for (int s = 0; s < 4; ++s) {
                int gx = __shfl(rcN.x, s * 4 + g4, 64);
                int gy = __shfl(rcN.y, s * 4 + g4, 64);
                ga[s] = *(const s16x8*)&xa[(size_t)gx * HD + r16 * 8];
                gb[s] = *(const s16x8*)&xb[(size_t)gy * HD + r16 * 8];
            }
        }

        // ---- 9. segmented reduce over sorted cols -> atomics (b32 packed)
        {
            int c0 = 2 * lane;  // col pair (c0, c0+1)
            int cur = secw[0];
            unsigned int pv = *(const unsigned int*)&stg[c0];
            float run0 = bf2f((unsigned short)(pv & 0xffff));
            float run1 = bf2f((unsigned short)(pv >> 16));
            #pragma unroll
            for (int e = 1; e < 16; ++e) {
                int c = secw[e];
                unsigned int qv = *(const unsigned int*)&stg[e * 136 + c0];
                float v0 = bf2f((unsigned short)(qv & 0xffff));
                float v1 = bf2f((unsigned short)(qv >> 16));
                if (c != cur) {  // wave-uniform
                    unsafeAtomicAdd(&agg[(size_t)cur * HD + c0], run0);
                    unsafeAtomicAdd(&agg[(size_t)cur * HD + c0 + 1], run1);
                    cur = c; run0 = v0; run1 = v1;
                } else { run0 += v0; run1 += v1; }
            }
            unsafeAtomicAdd(&agg[(size_t)cur * HD + c0], run0);
            unsafeAtomicAdd(&agg[(size_t)cur * HD + c0 + 1], run1);
        }
        WFENCE();

        rc = rcN; dp0 = dp0N; dp1 = dp1N; dp2 = dp2N;
    }
}

// ---------------------------------------------------------------------------
// stage 3 (FUSED): out = relu(x@uw1a + agg@uw1b + ub1) @ uw2 + ub2
// t stays in per-wave LDS (never touches HBM). 512 thr, 1 block/CU, 8 waves.
// ---------------------------------------------------------------------------
__global__ __launch_bounds__(512, 2) void upd_kernel(
    const float* __restrict__ x, const float* __restrict__ agg,
    const float* __restrict__ uw1, const float* __restrict__ ub1,
    const float* __restrict__ uw2, const float* __restrict__ ub2,
    float* __restrict__ out)
{
    __shared__ __align__(16) unsigned short sB1[128 * 264];   // uw1 [c][k<256]
    __shared__ __align__(16) unsigned short sB2[128 * 136];   // uw2 [c][k<128]
    __shared__ __align__(16) unsigned short sSt[8][16 * 136]; // per-wave t tile

    int tid = threadIdx.x;
    for (int idx = tid; idx < 256 * 128; idx += 512) {
        int c = idx & 127, k = idx >> 7;
        sB1[c * 264 + k] = f2bf(uw1[k * 128 + c]);
    }
    for (int idx = tid; idx < 128 * 128; idx += 512) {
        int c = idx & 127, k = idx >> 7;
        sB2[c * 136 + k] = f2bf(uw2[k * 128 + c]);
    }
    __syncthreads();

    int lane = tid & 63, wv = tid >> 6;
    int r16 = lane & 15, g4 = lane >> 4;
    unsigned short* st = sSt[wv];
    float ub1r[8], ub2r[8];
    #pragma unroll
    for (int tc = 0; tc < 8; ++tc) {
        ub1r[tc] = ub1[tc * 16 + r16];
        ub2r[tc] = ub2[tc * 16 + r16];
    }

    const int NT = NN / 16;  // 3125
    for (int t = blockIdx.x * 8 + wv; t < NT; t += gridDim.x * 8) {
        int r0 = t * 16;
        int row = r0 + r16;
        s16x8 a[8];
        #pragma unroll
        for (int ks = 0; ks < 8; ++ks) {
            const float* p = (ks < 4) ? &x[(size_t)row * HD + ks * 32 + g4 * 8]
                                      : &agg[(size_t)row * HD + (ks - 4) * 32 + g4 * 8];
            float4 v0 = *(const float4*)p;
            float4 v1 = *(const float4*)(p + 4);
            union { s16x8 v; unsigned int u[4]; } av;
            av.u[0] = f2bf2(v0.x, v0.y); av.u[1] = f2bf2(v0.z, v0.w);
            av.u[2] = f2bf2(v1.x, v1.y); av.u[3] = f2bf2(v1.z, v1.w);
            a[ks] = av.v;
        }
        // GEMM1: t = relu(x@uw1a + agg@uw1b + ub1) -> st (bf16)
        #pragma unroll
        for (int tc = 0; tc < 8; ++tc) {
            int col = tc * 16 + r16;
            float bv = ub1r[tc];
            f32x4 acc = {bv, bv, bv, bv};
            #pragma unroll
            for (int ks = 0; ks < 8; ++ks) {
                s16x8 b = *(const s16x8*)&sB1[col * 264 + ks * 32 + g4 * 8];
                acc = __builtin_amdgcn_mfma_f32_16x16x32_bf16(a[ks], b, acc, 0, 0, 0);
            }
            #pragma unroll
            for (int j = 0; j < 4; ++j)
                st[(g4 * 4 + j) * 136 + col] = f2bf(fmaxf(acc[j], 0.f));
        }
        WFENCE();
        // A-frags for GEMM2
        s16x8 a2[4];
        #pragma unroll
        for (int ks = 0; ks < 4; ++ks)
            a2[ks] = *(const s16x8*)&st[r16 * 136 + ks * 32 + g4 * 8];
        WFENCE();
        // GEMM2: out = t @ uw2 + ub2 (f32 coalesced stores)
        #pragma unroll
        for (int tc = 0; tc < 8; ++tc) {
            int col = tc * 16 + r16;
            float bv = ub2r[tc];
            f32x4 acc = {bv, bv, bv, bv};
            #pragma unroll
            for (int ks = 0; ks < 4; ++ks) {
                s16x8 b = *(const s16x8*)&sB2[col * 136 + ks * 32 + g4 * 8];
                acc = __builtin_amdgcn_mfma_f32_16x16x32_bf16(a2[ks], b, acc, 0, 0, 0);
            }
            #pragma unroll
            for (int j = 0; j < 4; ++j)
                out[(size_t)(r0 + g4 * 4 + j) * HD + col] = acc[j];
        }
    }
}

// ---------------------------------------------------------------------------
extern "C" void kernel_launch(void* const* d_in, const int* in_sizes, int n_in,
                              void* d_out, int out_size, void* d_ws, size_t ws_size,
                              hipStream_t stream)
{
    const float* x   = (const float*)d_in[0];
    const float* pos = (const float*)d_in[1];
    const int*   ei  = (const int*)d_in[2];
    const float* pw1 = (const float*)d_in[3];
    const float* pb1 = (const float*)d_in[4];
    const float* pw2 = (const float*)d_in[5];
    const float* pb2 = (const float*)d_in[6];
    const float* mw1 = (const float*)d_in[7];
    const float* mb1 = (const float*)d_in[8];
    const float* mw2 = (const float*)d_in[9];
    const float* mb2 = (const float*)d_in[10];
    const float* uw1 = (const float*)d_in[11];
    const float* ub1 = (const float*)d_in[12];
    const float* uw2 = (const float*)d_in[13];
    const float* ub2 = (const float*)d_in[14];
    float* out = (float*)d_out;

    char* ws = (char*)d_ws;
    float*          agg    = (float*)(ws);                      // 25,600,000 B
    unsigned short* xa     = (unsigned short*)(ws + 25600000);  // 12,800,000 B
    unsigned short* xb     = (unsigned short*)(ws + 38400000);  // 12,800,000 B
    float*          Wpc    = (float*)(ws + 51200000);           // 16,384 B
    float*          bcv    = (float*)(ws + 51216384);           // 512 B
    int*            cnt    = (int*)(ws + 51216896);             // 200,704 B
    int*            cursor = (int*)(ws + 51417600);             // 200,704 B
    int*            bsum   = (int*)(ws + 51618304);             // 256 B
    int2*           sRC    = (int2*)(ws + 51618560);            // 6,400,000 B

    hipMemsetAsync(agg, 0, (size_t)NN * HD * sizeof(float), stream);
    hipMemsetAsync(cnt, 0, NN * sizeof(int), stream);
    hist_kernel<<<(NE / 2 + 255) / 256, 256, 0, stream>>>(ei, cnt);
    scan1_kernel<<<SCAN_BLOCKS, 256, 0, stream>>>(cnt, cursor, bsum);
    scan2_kernel<<<1, 64, 0, stream>>>(bsum);
    scan3_kernel<<<SCAN_BLOCKS, 256, 0, stream>>>(cursor, bsum);
    prep_kernel<<<1, 256, 0, stream>>>(pw2, pb2, mw1, mb1, Wpc, bcv);
    scatter_kernel<<<(NE / 2 + 255) / 256, 256, 0, stream>>>(ei, cursor, sRC);
    node_pre_kernel<<<512, 256, 0, stream>>>(x, mw1, xa, xb);
    edge_kernel<<<512, 256, 0, stream>>>(pos, sRC, pw1, pb1, mw2, mb2, xa, xb, Wpc, bcv, agg);
    upd_kernel<<<256, 512, 0, stream>>>(x, agg, uw1, ub1, uw2, ub2, out);
}

// Round 8
// 278.402 us; speedup vs baseline: 1.3155x; 1.1331x over previous
//
#include <hip/hip_runtime.h>
#include <hip/hip_bf16.h>

#define NN 50000
#define NE 800000
#define HD 128
#define SCAN_CHUNK 1024
#define SCAN_BLOCKS ((NN + SCAN_CHUNK - 1) / SCAN_CHUNK)  // 49

typedef __attribute__((ext_vector_type(8))) short s16x8;
typedef __attribute__((ext_vector_type(4))) float f32x4;

static __device__ __forceinline__ unsigned short f2bf(float f) {
    unsigned int u = __float_as_uint(f);
    u = (u + 0x7FFFu + ((u >> 16) & 1u)) >> 16;
    return (unsigned short)u;
}
static __device__ __forceinline__ float bf2f(unsigned short h) {
    return __uint_as_float(((unsigned int)h) << 16);
}
static __device__ __forceinline__ unsigned int f2bf2(float lo, float hi) {
    __hip_bfloat162 h = __float22bfloat162_rn(make_float2(lo, hi));
    return *reinterpret_cast<unsigned int*>(&h);
}

// wave-level LDS fence: drain this wave's LDS ops, block compiler reordering.
#define WFENCE() do { asm volatile("s_waitcnt lgkmcnt(0)" ::: "memory"); \
                      __builtin_amdgcn_sched_barrier(0); } while (0)

// ---------------------------------------------------------------------------
// prep: Wpc = pw2 @ mw1[256:288,:]  (32x128), bc = pb2 @ mw1[256:288,:] + mb1
// ---------------------------------------------------------------------------
__global__ void prep_kernel(const float* __restrict__ pw2, const float* __restrict__ pb2,
                            const float* __restrict__ mw1, const float* __restrict__ mb1,
                            float* __restrict__ Wpc, float* __restrict__ bc)
{
    int tid = threadIdx.x;
    for (int idx = tid; idx < 32 * 128; idx += 256) {
        int j = idx >> 7, k = idx & 127;
        float s = 0.f;
        #pragma unroll 8
        for (int i = 0; i < 32; ++i) s += pw2[j * 32 + i] * mw1[(256 + i) * 128 + k];
        Wpc[idx] = s;
    }
    if (tid < 128) {
        float s = mb1[tid];
        #pragma unroll 8
        for (int i = 0; i < 32; ++i) s += pb2[i] * mw1[(256 + i) * 128 + tid];
        bc[tid] = s;
    }
}

// ---------------------------------------------------------------------------
// hist: count edges per destination col (2 edges/thread, vector loads)
// ---------------------------------------------------------------------------
__global__ void hist_kernel(const int* __restrict__ ei, int* __restrict__ cnt)
{
    __shared__ int sIdx64;
    if (threadIdx.x == 0) {
        int z = 1;
        for (int k = 0; k < 16; ++k) if (ei[2 * k + 1] != 0) z = 0;
        sIdx64 = z;
    }
    __syncthreads();
    int g = blockIdx.x * 256 + threadIdx.x;
    if (g >= NE / 2) return;
    int e0 = g * 2;
    int c0, c1;
    if (sIdx64) { int4 q = *(const int4*)&ei[2 * NE + 2 * e0]; c0 = q.x; c1 = q.z; }
    else        { int2 q = *(const int2*)&ei[NE + e0];         c0 = q.x; c1 = q.y; }
    atomicAdd(&cnt[c0], 1);
    atomicAdd(&cnt[c1], 1);
}

// ---------------------------------------------------------------------------
// parallel exclusive scan
// ---------------------------------------------------------------------------
__global__ void scan1_kernel(const int* __restrict__ cnt, int* __restrict__ cursor,
                             int* __restrict__ bsum)
{
    __shared__ int tot[256];
    int b = blockIdx.x, t = threadIdx.x;
    int i0 = b * SCAN_CHUNK + t * 4;
    int v[4];
    #pragma unroll
    for (int k = 0; k < 4; ++k) v[k] = (i0 + k < NN) ? cnt[i0 + k] : 0;
    tot[t] = v[0] + v[1] + v[2] + v[3];
    __syncthreads();
    if (t == 0) {
        int run = 0;
        for (int i = 0; i < 256; ++i) { int x = tot[i]; tot[i] = run; run += x; }
        bsum[b] = run;
    }
    __syncthreads();
    int p = tot[t];
    #pragma unroll
    for (int k = 0; k < 4; ++k) {
        if (i0 + k < NN) cursor[i0 + k] = p;
        p += v[k];
    }
}

__global__ void scan2_kernel(int* __restrict__ bsum)
{
    if (threadIdx.x == 0) {
        int run = 0;
        for (int i = 0; i < SCAN_BLOCKS; ++i) { int x = bsum[i]; bsum[i] = run; run += x; }
    }
}

__global__ void scan3_kernel(int* __restrict__ cursor, const int* __restrict__ bsum)
{
    int b = blockIdx.x, t = threadIdx.x;
    int carry = bsum[b];
    int i0 = b * SCAN_CHUNK + t * 4;
    #pragma unroll
    for (int k = 0; k < 4; ++k)
        if (i0 + k < NN) cursor[i0 + k] += carry;
}

// ---------------------------------------------------------------------------
// scatter: place (r,c) pairs at sorted-by-c positions (2 edges/thread)
// ---------------------------------------------------------------------------
__global__ void scatter_kernel(const int* __restrict__ ei,
                               int* __restrict__ cursor, int2* __restrict__ sRC)
{
    __shared__ int sIdx64;
    if (threadIdx.x == 0) {
        int z = 1;
        for (int k = 0; k < 16; ++k) if (ei[2 * k + 1] != 0) z = 0;
        sIdx64 = z;
    }
    __syncthreads();
    int g = blockIdx.x * 256 + threadIdx.x;
    if (g >= NE / 2) return;
    int e0 = g * 2;
    int r0, r1, c0, c1;
    if (sIdx64) {
        int4 qr = *(const int4*)&ei[2 * e0];           r0 = qr.x; r1 = qr.z;
        int4 qc = *(const int4*)&ei[2 * NE + 2 * e0];  c0 = qc.x; c1 = qc.z;
    } else {
        int2 qr = *(const int2*)&ei[e0];       r0 = qr.x; r1 = qr.y;
        int2 qc = *(const int2*)&ei[NE + e0];  c0 = qc.x; c1 = qc.y;
    }
    int p0 = atomicAdd(&cursor[c0], 1);
    sRC[p0] = make_int2(r0, c0);
    int p1 = atomicAdd(&cursor[c1], 1);
    sRC[p1] = make_int2(r1, c1);
}

// ---------------------------------------------------------------------------
// stage 1: xa = bf16(x @ mw1[0:128,:]), xb = bf16(x @ mw1[128:256,:])
// coalesced bf16 stores via per-wave LDS staging.
// ---------------------------------------------------------------------------
__global__ __launch_bounds__(256, 2) void node_pre_kernel(
    const float* __restrict__ x, const float* __restrict__ mw1,
    unsigned short* __restrict__ xa, unsigned short* __restrict__ xb)
{
    __shared__ __align__(16) unsigned short sB[256 * 136];   // [c<256][k<128]
    __shared__ __align__(16) unsigned short sSt[4][16 * 64];

    int tid = threadIdx.x;
    for (int idx = tid; idx < 256 * 128; idx += 256) {
        int c = idx & 255, k = idx >> 8;
        float v = (c < 128) ? mw1[k * 128 + c] : mw1[(128 + k) * 128 + (c - 128)];
        sB[c * 136 + k] = f2bf(v);
    }
    __syncthreads();

    int lane = tid & 63, wv = tid >> 6;
    int r16 = lane & 15, g4 = lane >> 4;
    unsigned short* st = sSt[wv];
    const int NT = NN / 16;  // 3125

    for (int t = blockIdx.x * 4 + wv; t < NT; t += gridDim.x * 4) {
        int r0 = t * 16;
        int row = r0 + r16;
        s16x8 a[4];
        #pragma unroll
        for (int ks = 0; ks < 4; ++ks) {
            const float* p = &x[(size_t)row * HD + ks * 32 + g4 * 8];
            float4 v0 = *(const float4*)p;
            float4 v1 = *(const float4*)(p + 4);
            union { s16x8 v; unsigned int u[4]; } av;
            av.u[0] = f2bf2(v0.x, v0.y); av.u[1] = f2bf2(v0.z, v0.w);
            av.u[2] = f2bf2(v1.x, v1.y); av.u[3] = f2bf2(v1.z, v1.w);
            a[ks] = av.v;
        }
        #pragma unroll
        for (int grp = 0; grp < 4; ++grp) {
            #pragma unroll
            for (int tc2 = 0; tc2 < 4; ++tc2) {
                int tc = grp * 4 + tc2;
                int col = tc * 16 + r16;
                f32x4 acc = {0.f, 0.f, 0.f, 0.f};
                #pragma unroll
                for (int ks = 0; ks < 4; ++ks) {
                    s16x8 b = *(const s16x8*)&sB[col * 136 + ks * 32 + g4 * 8];
                    acc = __builtin_amdgcn_mfma_f32_16x16x32_bf16(a[ks], b, acc, 0, 0, 0);
                }
                #pragma unroll
                for (int j = 0; j < 4; ++j)
                    st[(g4 * 4 + j) * 64 + tc2 * 16 + r16] = f2bf(acc[j]);
            }
            WFENCE();
            unsigned short* dst = (grp < 2) ? xa : xb;
            int ch = (grp & 1) * 64;
            #pragma unroll
            for (int i = 0; i < 2; ++i) {
                int idx = i * 512 + lane * 8;
                int rr = idx >> 6, cc = idx & 63;
                *(s16x8*)&dst[(size_t)(r0 + rr) * HD + ch + cc] = *(const s16x8*)&st[idx];
            }
            WFENCE();
        }
    }
}

// ---------------------------------------------------------------------------
// stage 2 (edges, SORTED by col): r3-proven config (grid 512, lb(256,2),
// separate sSTG/sHR, scalar lane/lane+64 segred) + DEEP pipeline:
// meta 2 tiles ahead, gathers issued right after staging (full-body cover).
// ---------------------------------------------------------------------------
__global__ __launch_bounds__(256, 2) void edge_kernel(
    const float* __restrict__ pos, const int2* __restrict__ sRC,
    const float* __restrict__ pw1, const float* __restrict__ pb1,
    const float* __restrict__ mw2, const float* __restrict__ mb2,
    const unsigned short* __restrict__ xa, const unsigned short* __restrict__ xb,
    const float* __restrict__ Wpc, const float* __restrict__ bc,
    float* __restrict__ agg)
{
    __shared__ __align__(16) unsigned short sB[128 * 136];      // mw2 [c][k]
    __shared__ __align__(16) unsigned short sSTG[4][16 * 136];  // staging / msg
    __shared__ __align__(16) unsigned short sHR[4][16 * 136];   // relu(h1)
    __shared__ int sECs[4][16];

    int tid = threadIdx.x;
    for (int idx = tid; idx < 128 * 128; idx += 256) {
        int c = idx & 127, k = idx >> 7;
        sB[c * 136 + k] = f2bf(mw2[k * 128 + c]);
    }
    __syncthreads();  // only block barrier

    int lane = tid & 63, wv = tid >> 6;
    int r16 = lane & 15, g4 = lane >> 4;
    unsigned short* stg = sSTG[wv];
    unsigned short* hrb = sHR[wv];
    int* secw = sECs[wv];

    s16x8 wr[8];
    #pragma unroll
    for (int tc = 0; tc < 8; ++tc) {
        s16x8 w;
        #pragma unroll
        for (int i = 0; i < 8; ++i)
            w[i] = (short)f2bf(Wpc[(g4 * 8 + i) * 128 + tc * 16 + r16]);
        wr[tc] = w;
    }
    float pw10[8], pw11[8], pw12[8], pb1r[8], bcg[8], mb2r[8];
    #pragma unroll
    for (int i = 0; i < 8; ++i) {
        int k = g4 * 8 + i;
        pw10[i] = pw1[k]; pw11[i] = pw1[32 + k]; pw12[i] = pw1[64 + k];
        pb1r[i] = pb1[k];
        bcg[i] = bc[r16 * 8 + i];
    }
    #pragma unroll
    for (int tc = 0; tc < 8; ++tc) mb2r[tc] = mb2[tc * 16 + r16];

    const int NW = gridDim.x * 4;
    const int NT = NE / 16;  // 50000
    int gw = blockIdx.x * 4 + wv;
    if (gw >= NT) return;

    // prologue: meta t, meta t+1, gathers t, pos-diffs t
    int2 rc = sRC[gw * 16 + r16];
    int2 rcN = rc;
    if (gw + NW < NT) rcN = sRC[(gw + NW) * 16 + r16];
    float dp0 = pos[rc.x * 3 + 0] - pos[rc.y * 3 + 0];
    float dp1 = pos[rc.x * 3 + 1] - pos[rc.y * 3 + 1];
    float dp2 = pos[rc.x * 3 + 2] - pos[rc.y * 3 + 2];
    s16x8 ga[4], gb[4];
    #pragma unroll
    for (int s = 0; s < 4; ++s) {
        int gx = __shfl(rc.x, s * 4 + g4, 64);
        int gy = __shfl(rc.y, s * 4 + g4, 64);
        ga[s] = *(const s16x8*)&xa[(size_t)gx * HD + r16 * 8];
        gb[s] = *(const s16x8*)&xb[(size_t)gy * HD + r16 * 8];
    }

    for (int t = gw; t < NT; t += NW) {
        bool hn  = (t + NW) < NT;
        bool hn2 = (t + 2 * NW) < NT;

        // ---- 1. staging: bf16(xa[row]+xb[col]+bc) -> stg
        #pragma unroll
        for (int s = 0; s < 4; ++s) {
            union { s16x8 v; unsigned int u[4]; } o;
            #pragma unroll
            for (int i2 = 0; i2 < 4; ++i2) {
                float v0 = bf2f((unsigned short)ga[s][2 * i2]) +
                           bf2f((unsigned short)gb[s][2 * i2]) + bcg[2 * i2];
                float v1 = bf2f((unsigned short)ga[s][2 * i2 + 1]) +
                           bf2f((unsigned short)gb[s][2 * i2 + 1]) + bcg[2 * i2 + 1];
                o.u[i2] = f2bf2(v0, v1);
            }
            *(s16x8*)&stg[(s * 4 + g4) * 136 + r16 * 8] = o.v;
        }
        if (lane < 16) secw[lane] = rc.y;
        WFENCE();

        // ---- 2. EARLY next-tile gathers (ga/gb free; covered by full body)
        if (hn) {
            #pragma unroll
            for (int s = 0; s < 4; ++s) {
                int gx = __shfl(rcN.x, s * 4 + g4, 64);
                int gy = __shfl(rcN.y, s * 4 + g4, 64);
                ga[s] = *(const s16x8*)&xa[(size_t)gx * HD + r16 * 8];
                gb[s] = *(const s16x8*)&xb[(size_t)gy * HD + r16 * 8];
            }
        }

        // ---- 3. meta for t+2 (consumed as rcN next iter)
        int2 rcN2 = rcN;
        if (hn2) rcN2 = sRC[(t + 2 * NW) * 16 + r16];

        // ---- 4. pos diffs for t+1
        float dp0N = 0.f, dp1N = 0.f, dp2N = 0.f;
        if (hn) {
            dp0N = pos[rcN.x * 3 + 0] - pos[rcN.y * 3 + 0];
            dp1N = pos[rcN.x * 3 + 1] - pos[rcN.y * 3 + 1];
            dp2N = pos[rcN.x * 3 + 2] - pos[rcN.y * 3 + 2];
        }

        // ---- 5. pos-MLP layer1 in A-frag layout
        union { s16x8 v; unsigned int u[4]; } apf;
        #pragma unroll
        for (int i2 = 0; i2 < 4; ++i2) {
            int i = 2 * i2;
            float v0 = fmaf(dp0, pw10[i], fmaf(dp1, pw11[i], fmaf(dp2, pw12[i], pb1r[i])));
            float v1 = fmaf(dp0, pw10[i+1], fmaf(dp1, pw11[i+1], fmaf(dp2, pw12[i+1], pb1r[i+1])));
            apf.u[i2] = f2bf2(fmaxf(v0, 0.f), fmaxf(v1, 0.f));
        }

        // ---- 6. GEMM1: h1 = pf@Wpc + stg ; relu -> hrb
        #pragma unroll
        for (int tc = 0; tc < 8; ++tc) {
            f32x4 z = {0.f, 0.f, 0.f, 0.f};
            f32x4 a1 = __builtin_amdgcn_mfma_f32_16x16x32_bf16(apf.v, wr[tc], z, 0, 0, 0);
            #pragma unroll
            for (int j = 0; j < 4; ++j) {
                int e = g4 * 4 + j, col = tc * 16 + r16;
                float v = a1[j] + bf2f(stg[e * 136 + col]);
                hrb[e * 136 + col] = f2bf(fmaxf(v, 0.f));
            }
        }
        WFENCE();

        // ---- 7. A-frags of GEMM2 from hrb
        s16x8 a2[4];
        #pragma unroll
        for (int ks = 0; ks < 4; ++ks)
            a2[ks] = *(const s16x8*)&hrb[r16 * 136 + ks * 32 + g4 * 8];

        // ---- 8. GEMM2: msg = HR @ mw2 + mb2 -> stg (in-order per-wave LDS)
        #pragma unroll
        for (int tc = 0; tc < 8; ++tc) {
            f32x4 acc = {mb2r[tc], mb2r[tc], mb2r[tc], mb2r[tc]};
            #pragma unroll
            for (int ks = 0; ks < 4; ++ks) {
                s16x8 b = *(const s16x8*)&sB[(tc * 16 + r16) * 136 + ks * 32 + g4 * 8];
                acc = __builtin_amdgcn_mfma_f32_16x16x32_bf16(a2[ks], b, acc, 0, 0, 0);
            }
            #pragma unroll
            for (int j = 0; j < 4; ++j)
                stg[(g4 * 4 + j) * 136 + tc * 16 + r16] = f2bf(acc[j]);
        }
        WFENCE();

        // ---- 9. segmented reduce, contiguous (lane, lane+64) atomics
        {
            int f0 = lane, f1 = lane + 64;
            int cur = secw[0];
            float run0 = bf2f(stg[f0]);
            float run1 = bf2f(stg[f1]);
            #pragma unroll
            for (int e = 1; e < 16; ++e) {
                int c = secw[e];
                float v0 = bf2f(stg[e * 136 + f0]);
                float v1 = bf2f(stg[e * 136 + f1]);
                if (c != cur) {  // wave-uniform
                    unsafeAtomicAdd(&agg[(size_t)cur * HD + f0], run0);
                    unsafeAtomicAdd(&agg[(size_t)cur * HD + f1], run1);
                    cur = c; run0 = v0; run1 = v1;
                } else { run0 += v0; run1 += v1; }
            }
            unsafeAtomicAdd(&agg[(size_t)cur * HD + f0], run0);
            unsafeAtomicAdd(&agg[(size_t)cur * HD + f1], run1);
        }
        WFENCE();

        rc = rcN; rcN = rcN2; dp0 = dp0N; dp1 = dp1N; dp2 = dp2N;
    }
}

// ---------------------------------------------------------------------------
// stage 3 (FUSED): out = relu(x@uw1a + agg@uw1b + ub1) @ uw2 + ub2
// t stays in per-wave LDS. 512 thr, 1 block/CU, 8 waves.
// ---------------------------------------------------------------------------
__global__ __launch_bounds__(512, 2) void upd_kernel(
    const float* __restrict__ x, const float* __restrict__ agg,
    const float* __restrict__ uw1, const float* __restrict__ ub1,
    const float* __restrict__ uw2, const float* __restrict__ ub2,
    float* __restrict__ out)
{
    __shared__ __align__(16) unsigned short sB1[128 * 264];   // uw1 [c][k<256]
    __shared__ __align__(16) unsigned short sB2[128 * 136];   // uw2 [c][k<128]
    __shared__ __align__(16) unsigned short sSt[8][16 * 136]; // per-wave t tile

    int tid = threadIdx.x;
    for (int idx = tid; idx < 256 * 128; idx += 512) {
        int c = idx & 127, k = idx >> 7;
        sB1[c * 264 + k] = f2bf(uw1[k * 128 + c]);
    }
    for (int idx = tid; idx < 128 * 128; idx += 512) {
        int c = idx & 127, k = idx >> 7;
        sB2[c * 136 + k] = f2bf(uw2[k * 128 + c]);
    }
    __syncthreads();

    int lane = tid & 63, wv = tid >> 6;
    int r16 = lane & 15, g4 = lane >> 4;
    unsigned short* st = sSt[wv];
    float ub1r[8], ub2r[8];
    #pragma unroll
    for (int tc = 0; tc < 8; ++tc) {
        ub1r[tc] = ub1[tc * 16 + r16];
        ub2r[tc] = ub2[tc * 16 + r16];
    }

    const int NT = NN / 16;  // 3125
    for (int t = blockIdx.x * 8 + wv; t < NT; t += gridDim.x * 8) {
        int r0 = t * 16;
        int row = r0 + r16;
        s16x8 a[8];
        #pragma unroll
        for (int ks = 0; ks < 8; ++ks) {
            const float* p = (ks < 4) ? &x[(size_t)row * HD + ks * 32 + g4 * 8]
                                      : &agg[(size_t)row * HD + (ks - 4) * 32 + g4 * 8];
            float4 v0 = *(const float4*)p;
            float4 v1 = *(const float4*)(p + 4);
            union { s16x8 v; unsigned int u[4]; } av;
            av.u[0] = f2bf2(v0.x, v0.y); av.u[1] = f2bf2(v0.z, v0.w);
            av.u[2] = f2bf2(v1.x, v1.y); av.u[3] = f2bf2(v1.z, v1.w);
            a[ks] = av.v;
        }
        // GEMM1: t = relu(x@uw1a + agg@uw1b + ub1) -> st (bf16)
        #pragma unroll
        for (int tc = 0; tc < 8; ++tc) {
            int col = tc * 16 + r16;
            float bv = ub1r[tc];
            f32x4 acc = {bv, bv, bv, bv};
            #pragma unroll
            for (int ks = 0; ks < 8; ++ks) {
                s16x8 b = *(const s16x8*)&sB1[col * 264 + ks * 32 + g4 * 8];
                acc = __builtin_amdgcn_mfma_f32_16x16x32_bf16(a[ks], b, acc, 0, 0, 0);
            }
            #pragma unroll
            for (int j = 0; j < 4; ++j)
                st[(g4 * 4 + j) * 136 + col] = f2bf(fmaxf(acc[j], 0.f));
        }
        WFENCE();
        // A-frags for GEMM2
        s16x8 a2[4];
        #pragma unroll
        for (int ks = 0; ks < 4; ++ks)
            a2[ks] = *(const s16x8*)&st[r16 * 136 + ks * 32 + g4 * 8];
        WFENCE();
        // GEMM2: out = t @ uw2 + ub2 (f32 coalesced stores)
        #pragma unroll
        for (int tc = 0; tc < 8; ++tc) {
            int col = tc * 16 + r16;
            float bv = ub2r[tc];
            f32x4 acc = {bv, bv, bv, bv};
            #pragma unroll
            for (int ks = 0; ks < 4; ++ks) {
                s16x8 b = *(const s16x8*)&sB2[col * 136 + ks * 32 + g4 * 8];
                acc = __builtin_amdgcn_mfma_f32_16x16x32_bf16(a2[ks], b, acc, 0, 0, 0);
            }
            #pragma unroll
            for (int j = 0; j < 4; ++j)
                out[(size_t)(r0 + g4 * 4 + j) * HD + col] = acc[j];
        }
    }
}

// ---------------------------------------------------------------------------
extern "C" void kernel_launch(void* const* d_in, const int* in_sizes, int n_in,
                              void* d_out, int out_size, void* d_ws, size_t ws_size,
                              hipStream_t stream)
{
    const float* x   = (const float*)d_in[0];
    const float* pos = (const float*)d_in[1];
    const int*   ei  = (const int*)d_in[2];
    const float* pw1 = (const float*)d_in[3];
    const float* pb1 = (const float*)d_in[4];
    const float* pw2 = (const float*)d_in[5];
    const float* pb2 = (const float*)d_in[6];
    const float* mw1 = (const float*)d_in[7];
    const float* mb1 = (const float*)d_in[8];
    const float* mw2 = (const float*)d_in[9];
    const float* mb2 = (const float*)d_in[10];
    const float* uw1 = (const float*)d_in[11];
    const float* ub1 = (const float*)d_in[12];
    const float* uw2 = (const float*)d_in[13];
    const float* ub2 = (const float*)d_in[14];
    float* out = (float*)d_out;

    char* ws = (char*)d_ws;
    float*          agg    = (float*)(ws);                      // 25,600,000 B
    unsigned short* xa     = (unsigned short*)(ws + 25600000);  // 12,800,000 B
    unsigned short* xb     = (unsigned short*)(ws + 38400000);  // 12,800,000 B
    float*          Wpc    = (float*)(ws + 51200000);           // 16,384 B
    float*          bcv    = (float*)(ws + 51216384);           // 512 B
    int*            cnt    = (int*)(ws + 51216896);             // 200,704 B
    int*            cursor = (int*)(ws + 51417600);             // 200,704 B
    int*            bsum   = (int*)(ws + 51618304);             // 256 B
    int2*           sRC    = (int2*)(ws + 51618560);            // 6,400,000 B

    hipMemsetAsync(agg, 0, (size_t)NN * HD * sizeof(float), stream);
    hipMemsetAsync(cnt, 0, NN * sizeof(int), stream);
    hist_kernel<<<(NE / 2 + 255) / 256, 256, 0, stream>>>(ei, cnt);
    scan1_kernel<<<SCAN_BLOCKS, 256, 0, stream>>>(cnt, cursor, bsum);
    scan2_kernel<<<1, 64, 0, stream>>>(bsum);
    scan3_kernel<<<SCAN_BLOCKS, 256, 0, stream>>>(cursor, bsum);
    prep_kernel<<<1, 256, 0, stream>>>(pw2, pb2, mw1, mb1, Wpc, bcv);
    scatter_kernel<<<(NE / 2 + 255) / 256, 256, 0, stream>>>(ei, cursor, sRC);
    node_pre_kernel<<<512, 256, 0, stream>>>(x, mw1, xa, xb);
    edge_kernel<<<512, 256, 0, stream>>>(pos, sRC, pw1, pb1, mw2, mb2, xa, xb, Wpc, bcv, agg);
    upd_kernel<<<256, 512, 0, stream>>>(x, agg, uw1, ub1, uw2, ub2, out);
}

// Round 9
// 248.555 us; speedup vs baseline: 1.4734x; 1.1201x over previous
//
#include <hip/hip_runtime.h>
#include <hip/hip_bf16.h>

#define NN 50000
#define NE 800000
#define HD 128
#define SCAN_CHUNK 1024
#define SCAN_BLOCKS ((NN + SCAN_CHUNK - 1) / SCAN_CHUNK)  // 49

typedef __attribute__((ext_vector_type(8))) short s16x8;
typedef __attribute__((ext_vector_type(4))) float f32x4;

static __device__ __forceinline__ unsigned short f2bf(float f) {
    unsigned int u = __float_as_uint(f);
    u = (u + 0x7FFFu + ((u >> 16) & 1u)) >> 16;
    return (unsigned short)u;
}
static __device__ __forceinline__ float bf2f(unsigned short h) {
    return __uint_as_float(((unsigned int)h) << 16);
}
static __device__ __forceinline__ unsigned int f2bf2(float lo, float hi) {
    __hip_bfloat162 h = __float22bfloat162_rn(make_float2(lo, hi));
    return *reinterpret_cast<unsigned int*>(&h);
}

// wave-level LDS fence: drain this wave's LDS ops, block compiler reordering.
#define WFENCE() do { asm volatile("s_waitcnt lgkmcnt(0)" ::: "memory"); \
                      __builtin_amdgcn_sched_barrier(0); } while (0)

// ---------------------------------------------------------------------------
// prep: Wpc = pw2 @ mw1[256:288,:]  (32x128), bc = pb2 @ mw1[256:288,:] + mb1
// ---------------------------------------------------------------------------
__global__ void prep_kernel(const float* __restrict__ pw2, const float* __restrict__ pb2,
                            const float* __restrict__ mw1, const float* __restrict__ mb1,
                            float* __restrict__ Wpc, float* __restrict__ bc)
{
    int tid = threadIdx.x;
    for (int idx = tid; idx < 32 * 128; idx += 256) {
        int j = idx >> 7, k = idx & 127;
        float s = 0.f;
        #pragma unroll 8
        for (int i = 0; i < 32; ++i) s += pw2[j * 32 + i] * mw1[(256 + i) * 128 + k];
        Wpc[idx] = s;
    }
    if (tid < 128) {
        float s = mb1[tid];
        #pragma unroll 8
        for (int i = 0; i < 32; ++i) s += pb2[i] * mw1[(256 + i) * 128 + tid];
        bc[tid] = s;
    }
}

// ---------------------------------------------------------------------------
// hist: count edges per destination col (cnt == deg, reused by aggmm)
// ---------------------------------------------------------------------------
__global__ void hist_kernel(const int* __restrict__ ei, int* __restrict__ cnt)
{
    __shared__ int sIdx64;
    if (threadIdx.x == 0) {
        int z = 1;
        for (int k = 0; k < 16; ++k) if (ei[2 * k + 1] != 0) z = 0;
        sIdx64 = z;
    }
    __syncthreads();
    int g = blockIdx.x * 256 + threadIdx.x;
    if (g >= NE / 2) return;
    int e0 = g * 2;
    int c0, c1;
    if (sIdx64) { int4 q = *(const int4*)&ei[2 * NE + 2 * e0]; c0 = q.x; c1 = q.z; }
    else        { int2 q = *(const int2*)&ei[NE + e0];         c0 = q.x; c1 = q.y; }
    atomicAdd(&cnt[c0], 1);
    atomicAdd(&cnt[c1], 1);
}

// ---------------------------------------------------------------------------
// parallel exclusive scan
// ---------------------------------------------------------------------------
__global__ void scan1_kernel(const int* __restrict__ cnt, int* __restrict__ cursor,
                             int* __restrict__ bsum)
{
    __shared__ int tot[256];
    int b = blockIdx.x, t = threadIdx.x;
    int i0 = b * SCAN_CHUNK + t * 4;
    int v[4];
    #pragma unroll
    for (int k = 0; k < 4; ++k) v[k] = (i0 + k < NN) ? cnt[i0 + k] : 0;
    tot[t] = v[0] + v[1] + v[2] + v[3];
    __syncthreads();
    if (t == 0) {
        int run = 0;
        for (int i = 0; i < 256; ++i) { int x = tot[i]; tot[i] = run; run += x; }
        bsum[b] = run;
    }
    __syncthreads();
    int p = tot[t];
    #pragma unroll
    for (int k = 0; k < 4; ++k) {
        if (i0 + k < NN) cursor[i0 + k] = p;
        p += v[k];
    }
}

__global__ void scan2_kernel(int* __restrict__ bsum)
{
    if (threadIdx.x == 0) {
        int run = 0;
        for (int i = 0; i < SCAN_BLOCKS; ++i) { int x = bsum[i]; bsum[i] = run; run += x; }
    }
}

__global__ void scan3_kernel(int* __restrict__ cursor, const int* __restrict__ bsum)
{
    int b = blockIdx.x, t = threadIdx.x;
    int carry = bsum[b];
    int i0 = b * SCAN_CHUNK + t * 4;
    #pragma unroll
    for (int k = 0; k < 4; ++k)
        if (i0 + k < NN) cursor[i0 + k] += carry;
}

// ---------------------------------------------------------------------------
// scatter: place (r,c) pairs at sorted-by-c positions
// ---------------------------------------------------------------------------
__global__ void scatter_kernel(const int* __restrict__ ei,
                               int* __restrict__ cursor, int2* __restrict__ sRC)
{
    __shared__ int sIdx64;
    if (threadIdx.x == 0) {
        int z = 1;
        for (int k = 0; k < 16; ++k) if (ei[2 * k + 1] != 0) z = 0;
        sIdx64 = z;
    }
    __syncthreads();
    int g = blockIdx.x * 256 + threadIdx.x;
    if (g >= NE / 2) return;
    int e0 = g * 2;
    int r0, r1, c0, c1;
    if (sIdx64) {
        int4 qr = *(const int4*)&ei[2 * e0];           r0 = qr.x; r1 = qr.z;
        int4 qc = *(const int4*)&ei[2 * NE + 2 * e0];  c0 = qc.x; c1 = qc.z;
    } else {
        int2 qr = *(const int2*)&ei[e0];       r0 = qr.x; r1 = qr.y;
        int2 qc = *(const int2*)&ei[NE + e0];  c0 = qc.x; c1 = qc.y;
    }
    int p0 = atomicAdd(&cursor[c0], 1);
    sRC[p0] = make_int2(r0, c0);
    int p1 = atomicAdd(&cursor[c1], 1);
    sRC[p1] = make_int2(r1, c1);
}

// ---------------------------------------------------------------------------
// stage 1: xa = bf16(x @ mw1_a), xb = bf16(x @ mw1_b + bc)  (bc folded!)
// ---------------------------------------------------------------------------
__global__ __launch_bounds__(256, 2) void node_pre_kernel(
    const float* __restrict__ x, const float* __restrict__ mw1,
    const float* __restrict__ bcv,
    unsigned short* __restrict__ xa, unsigned short* __restrict__ xb)
{
    __shared__ __align__(16) unsigned short sB[256 * 136];   // [c<256][k<128]
    __shared__ __align__(16) unsigned short sSt[4][16 * 64];

    int tid = threadIdx.x;
    for (int idx = tid; idx < 256 * 128; idx += 256) {
        int c = idx & 255, k = idx >> 8;
        float v = (c < 128) ? mw1[k * 128 + c] : mw1[(128 + k) * 128 + (c - 128)];
        sB[c * 136 + k] = f2bf(v);
    }
    __syncthreads();

    int lane = tid & 63, wv = tid >> 6;
    int r16 = lane & 15, g4 = lane >> 4;
    unsigned short* st = sSt[wv];
    float bcx[8];
    #pragma unroll
    for (int i = 0; i < 8; ++i) bcx[i] = bcv[i * 16 + r16];
    const int NT = NN / 16;  // 3125

    for (int t = blockIdx.x * 4 + wv; t < NT; t += gridDim.x * 4) {
        int r0 = t * 16;
        int row = r0 + r16;
        s16x8 a[4];
        #pragma unroll
        for (int ks = 0; ks < 4; ++ks) {
            const float* p = &x[(size_t)row * HD + ks * 32 + g4 * 8];
            float4 v0 = *(const float4*)p;
            float4 v1 = *(const float4*)(p + 4);
            union { s16x8 v; unsigned int u[4]; } av;
            av.u[0] = f2bf2(v0.x, v0.y); av.u[1] = f2bf2(v0.z, v0.w);
            av.u[2] = f2bf2(v1.x, v1.y); av.u[3] = f2bf2(v1.z, v1.w);
            a[ks] = av.v;
        }
        #pragma unroll
        for (int grp = 0; grp < 4; ++grp) {
            #pragma unroll
            for (int tc2 = 0; tc2 < 4; ++tc2) {
                int tc = grp * 4 + tc2;
                int col = tc * 16 + r16;
                f32x4 acc = {0.f, 0.f, 0.f, 0.f};
                #pragma unroll
                for (int ks = 0; ks < 4; ++ks) {
                    s16x8 b = *(const s16x8*)&sB[col * 136 + ks * 32 + g4 * 8];
                    acc = __builtin_amdgcn_mfma_f32_16x16x32_bf16(a[ks], b, acc, 0, 0, 0);
                }
                float badd = (grp >= 2) ? bcx[(grp - 2) * 4 + tc2] : 0.f;
                #pragma unroll
                for (int j = 0; j < 4; ++j)
                    st[(g4 * 4 + j) * 64 + tc2 * 16 + r16] = f2bf(acc[j] + badd);
            }
            WFENCE();
            unsigned short* dst = (grp < 2) ? xa : xb;
            int ch = (grp & 1) * 64;
            #pragma unroll
            for (int i = 0; i < 2; ++i) {
                int idx = i * 512 + lane * 8;
                int rr = idx >> 6, cc = idx & 63;
                *(s16x8*)&dst[(size_t)(r0 + rr) * HD + ch + cc] = *(const s16x8*)&st[idx];
            }
            WFENCE();
        }
    }
}

// ---------------------------------------------------------------------------
// stage 2 (edges, SORTED by col): GEMM2 hoisted out (distributes over the
// segment sum) -> per tile only: gather, pos-MLP, 8-MFMA GEMM1, relu,
// segmented-sum relu(h1) into aggH. No sB, no block barrier, 17.7 KB LDS.
// ---------------------------------------------------------------------------
__global__ __launch_bounds__(256, 3) void edge_kernel(
    const float* __restrict__ pos, const int2* __restrict__ sRC,
    const float* __restrict__ pw1, const float* __restrict__ pb1,
    const unsigned short* __restrict__ xa, const unsigned short* __restrict__ xb,
    const float* __restrict__ Wpc,
    float* __restrict__ aggH)
{
    __shared__ __align__(16) unsigned short sT[4][16 * 136];  // stg -> relu(h1)
    __shared__ int sECs[4][16];

    int tid = threadIdx.x;
    int lane = tid & 63, wv = tid >> 6;
    int r16 = lane & 15, g4 = lane >> 4;
    unsigned short* stg = sT[wv];
    int* secw = sECs[wv];

    s16x8 wr[8];
    #pragma unroll
    for (int tc = 0; tc < 8; ++tc) {
        s16x8 w;
        #pragma unroll
        for (int i = 0; i < 8; ++i)
            w[i] = (short)f2bf(Wpc[(g4 * 8 + i) * 128 + tc * 16 + r16]);
        wr[tc] = w;
    }
    float pw10[8], pw11[8], pw12[8], pb1r[8];
    #pragma unroll
    for (int i = 0; i < 8; ++i) {
        int k = g4 * 8 + i;
        pw10[i] = pw1[k]; pw11[i] = pw1[32 + k]; pw12[i] = pw1[64 + k];
        pb1r[i] = pb1[k];
    }

    const int NW = gridDim.x * 4;
    const int NT = NE / 16;  // 50000
    int gw = blockIdx.x * 4 + wv;
    if (gw >= NT) return;

    // prologue: meta t, meta t+1, gathers t, pos-diffs t
    int2 rc = sRC[gw * 16 + r16];
    int2 rcN = rc;
    if (gw + NW < NT) rcN = sRC[(gw + NW) * 16 + r16];
    float dp0 = pos[rc.x * 3 + 0] - pos[rc.y * 3 + 0];
    float dp1 = pos[rc.x * 3 + 1] - pos[rc.y * 3 + 1];
    float dp2 = pos[rc.x * 3 + 2] - pos[rc.y * 3 + 2];
    s16x8 ga[4], gb[4];
    #pragma unroll
    for (int s = 0; s < 4; ++s) {
        int gx = __shfl(rc.x, s * 4 + g4, 64);
        int gy = __shfl(rc.y, s * 4 + g4, 64);
        ga[s] = *(const s16x8*)&xa[(size_t)gx * HD + r16 * 8];
        gb[s] = *(const s16x8*)&xb[(size_t)gy * HD + r16 * 8];
    }

    for (int t = gw; t < NT; t += NW) {
        bool hn  = (t + NW) < NT;
        bool hn2 = (t + 2 * NW) < NT;

        // ---- 1. staging: bf16(xa[row] + xb'[col]) -> stg   (bc inside xb')
        #pragma unroll
        for (int s = 0; s < 4; ++s) {
            union { s16x8 v; unsigned int u[4]; } o;
            #pragma unroll
            for (int i2 = 0; i2 < 4; ++i2) {
                float v0 = bf2f((unsigned short)ga[s][2 * i2]) +
                           bf2f((unsigned short)gb[s][2 * i2]);
                float v1 = bf2f((unsigned short)ga[s][2 * i2 + 1]) +
                           bf2f((unsigned short)gb[s][2 * i2 + 1]);
                o.u[i2] = f2bf2(v0, v1);
            }
            *(s16x8*)&stg[(s * 4 + g4) * 136 + r16 * 8] = o.v;
        }
        if (lane < 16) secw[lane] = rc.y;
        WFENCE();

        // ---- 2. EARLY next-tile gathers (full-body latency cover)
        if (hn) {
            #pragma unroll
            for (int s = 0; s < 4; ++s) {
                int gx = __shfl(rcN.x, s * 4 + g4, 64);
                int gy = __shfl(rcN.y, s * 4 + g4, 64);
                ga[s] = *(const s16x8*)&xa[(size_t)gx * HD + r16 * 8];
                gb[s] = *(const s16x8*)&xb[(size_t)gy * HD + r16 * 8];
            }
        }

        // ---- 3. meta for t+2
        int2 rcN2 = rcN;
        if (hn2) rcN2 = sRC[(t + 2 * NW) * 16 + r16];

        // ---- 4. pos diffs for t+1
        float dp0N = 0.f, dp1N = 0.f, dp2N = 0.f;
        if (hn) {
            dp0N = pos[rcN.x * 3 + 0] - pos[rcN.y * 3 + 0];
            dp1N = pos[rcN.x * 3 + 1] - pos[rcN.y * 3 + 1];
            dp2N = pos[rcN.x * 3 + 2] - pos[rcN.y * 3 + 2];
        }

        // ---- 5. pos-MLP layer1 in A-frag layout
        union { s16x8 v; unsigned int u[4]; } apf;
        #pragma unroll
        for (int i2 = 0; i2 < 4; ++i2) {
            int i = 2 * i2;
            float v0 = fmaf(dp0, pw10[i], fmaf(dp1, pw11[i], fmaf(dp2, pw12[i], pb1r[i])));
            float v1 = fmaf(dp0, pw10[i+1], fmaf(dp1, pw11[i+1], fmaf(dp2, pw12[i+1], pb1r[i+1])));
            apf.u[i2] = f2bf2(fmaxf(v0, 0.f), fmaxf(v1, 0.f));
        }

        // ---- 6. GEMM1: h1 = pf@Wpc + stg ; relu -> same buffer (per-lane RMW)
        #pragma unroll
        for (int tc = 0; tc < 8; ++tc) {
            f32x4 z = {0.f, 0.f, 0.f, 0.f};
            f32x4 a1 = __builtin_amdgcn_mfma_f32_16x16x32_bf16(apf.v, wr[tc], z, 0, 0, 0);
            #pragma unroll
            for (int j = 0; j < 4; ++j) {
                int e = g4 * 4 + j, col = tc * 16 + r16;
                float v = a1[j] + bf2f(stg[e * 136 + col]);
                stg[e * 136 + col] = f2bf(fmaxf(v, 0.f));
            }
        }
        WFENCE();

        // ---- 7. segmented sum of relu(h1), contiguous (lane, lane+64) atomics
        {
            int f0 = lane, f1 = lane + 64;
            int cur = secw[0];
            float run0 = bf2f(stg[f0]);
            float run1 = bf2f(stg[f1]);
            #pragma unroll
            for (int e = 1; e < 16; ++e) {
                int c = secw[e];
                float v0 = bf2f(stg[e * 136 + f0]);
                float v1 = bf2f(stg[e * 136 + f1]);
                if (c != cur) {  // wave-uniform
                    unsafeAtomicAdd(&aggH[(size_t)cur * HD + f0], run0);
                    unsafeAtomicAdd(&aggH[(size_t)cur * HD + f1], run1);
                    cur = c; run0 = v0; run1 = v1;
                } else { run0 += v0; run1 += v1; }
            }
            unsafeAtomicAdd(&aggH[(size_t)cur * HD + f0], run0);
            unsafeAtomicAdd(&aggH[(size_t)cur * HD + f1], run1);
        }
        WFENCE();

        rc = rcN; rcN = rcN2; dp0 = dp0N; dp1 = dp1N; dp2 = dp2N;
    }
}

// ---------------------------------------------------------------------------
// stage 2b (hoisted GEMM2, per NODE): agg2 = bf16(aggH @ mw2 + deg*mb2)
// ---------------------------------------------------------------------------
__global__ __launch_bounds__(256, 2) void aggmm_kernel(
    const float* __restrict__ aggH, const int* __restrict__ cnt,
    const float* __restrict__ mw2, const float* __restrict__ mb2,
    unsigned short* __restrict__ agg2)
{
    __shared__ __align__(16) unsigned short sB[128 * 136];  // mw2 [c][k]
    __shared__ __align__(16) unsigned short sSt[4][16 * 64];

    int tid = threadIdx.x;
    for (int idx = tid; idx < 128 * 128; idx += 256) {
        int c = idx & 127, k = idx >> 7;
        sB[c * 136 + k] = f2bf(mw2[k * 128 + c]);
    }
    __syncthreads();

    int lane = tid & 63, wv = tid >> 6;
    int r16 = lane & 15, g4 = lane >> 4;
    unsigned short* st = sSt[wv];
    float mb2r[8];
    #pragma unroll
    for (int tc = 0; tc < 8; ++tc) mb2r[tc] = mb2[tc * 16 + r16];

    const int NT = NN / 16;  // 3125
    for (int t = blockIdx.x * 4 + wv; t < NT; t += gridDim.x * 4) {
        int r0 = t * 16;
        int row = r0 + r16;
        s16x8 a[4];
        #pragma unroll
        for (int ks = 0; ks < 4; ++ks) {
            const float* p = &aggH[(size_t)row * HD + ks * 32 + g4 * 8];
            float4 v0 = *(const float4*)p;
            float4 v1 = *(const float4*)(p + 4);
            union { s16x8 v; unsigned int u[4]; } av;
            av.u[0] = f2bf2(v0.x, v0.y); av.u[1] = f2bf2(v0.z, v0.w);
            av.u[2] = f2bf2(v1.x, v1.y); av.u[3] = f2bf2(v1.z, v1.w);
            a[ks] = av.v;
        }
        float cn[4];
        #pragma unroll
        for (int j = 0; j < 4; ++j) cn[j] = (float)cnt[r0 + g4 * 4 + j];
        #pragma unroll
        for (int half = 0; half < 2; ++half) {
            #pragma unroll
            for (int tc2 = 0; tc2 < 4; ++tc2) {
                int tc = half * 4 + tc2;
                int col = tc * 16 + r16;
                f32x4 acc;
                #pragma unroll
                for (int j = 0; j < 4; ++j) acc[j] = cn[j] * mb2r[tc];
                #pragma unroll
                for (int ks = 0; ks < 4; ++ks) {
                    s16x8 b = *(const s16x8*)&sB[col * 136 + ks * 32 + g4 * 8];
                    acc = __builtin_amdgcn_mfma_f32_16x16x32_bf16(a[ks], b, acc, 0, 0, 0);
                }
                #pragma unroll
                for (int j = 0; j < 4; ++j)
                    st[(g4 * 4 + j) * 64 + tc2 * 16 + r16] = f2bf(acc[j]);
            }
            WFENCE();
            #pragma unroll
            for (int i = 0; i < 2; ++i) {
                int idx = i * 512 + lane * 8;
                int rr = idx >> 6, cc = idx & 63;
                *(s16x8*)&agg2[(size_t)(r0 + rr) * HD + half * 64 + cc] = *(const s16x8*)&st[idx];
            }
            WFENCE();
        }
    }
}

// ---------------------------------------------------------------------------
// stage 3 (FUSED): out = relu(x@uw1a + agg2@uw1b + ub1) @ uw2 + ub2
// agg2 already bf16 -> direct A-frag loads.
// ---------------------------------------------------------------------------
__global__ __launch_bounds__(512, 2) void upd_kernel(
    const float* __restrict__ x, const unsigned short* __restrict__ agg2,
    const float* __restrict__ uw1, const float* __restrict__ ub1,
    const float* __restrict__ uw2, const float* __restrict__ ub2,
    float* __restrict__ out)
{
    __shared__ __align__(16) unsigned short sB1[128 * 264];   // uw1 [c][k<256]
    __shared__ __align__(16) unsigned short sB2[128 * 136];   // uw2 [c][k<128]
    __shared__ __align__(16) unsigned short sSt[8][16 * 136]; // per-wave t tile

    int tid = threadIdx.x;
    for (int idx = tid; idx < 256 * 128; idx += 512) {
        int c = idx & 127, k = idx >> 7;
        sB1[c * 264 + k] = f2bf(uw1[k * 128 + c]);
    }
    for (int idx = tid; idx < 128 * 128; idx += 512) {
        int c = idx & 127, k = idx >> 7;
        sB2[c * 136 + k] = f2bf(uw2[k * 128 + c]);
    }
    __syncthreads();

    int lane = tid & 63, wv = tid >> 6;
    int r16 = lane & 15, g4 = lane >> 4;
    unsigned short* st = sSt[wv];
    float ub1r[8], ub2r[8];
    #pragma unroll
    for (int tc = 0; tc < 8; ++tc) {
        ub1r[tc] = ub1[tc * 16 + r16];
        ub2r[tc] = ub2[tc * 16 + r16];
    }

    const int NT = NN / 16;  // 3125
    for (int t = blockIdx.x * 8 + wv; t < NT; t += gridDim.x * 8) {
        int r0 = t * 16;
        int row = r0 + r16;
        s16x8 a[8];
        #pragma unroll
        for (int ks = 0; ks < 4; ++ks) {
            const float* p = &x[(size_t)row * HD + ks * 32 + g4 * 8];
            float4 v0 = *(const float4*)p;
            float4 v1 = *(const float4*)(p + 4);
            union { s16x8 v; unsigned int u[4]; } av;
            av.u[0] = f2bf2(v0.x, v0.y); av.u[1] = f2bf2(v0.z, v0.w);
            av.u[2] = f2bf2(v1.x, v1.y); av.u[3] = f2bf2(v1.z, v1.w);
            a[ks] = av.v;
        }
        #pragma unroll
        for (int ks = 4; ks < 8; ++ks)
            a[ks] = *(const s16x8*)&agg2[(size_t)row * HD + (ks - 4) * 32 + g4 * 8];

        // GEMM1: t = relu(x@uw1a + agg2@uw1b + ub1) -> st (bf16)
        #pragma unroll
        for (int tc = 0; tc < 8; ++tc) {
            int col = tc * 16 + r16;
            float bv = ub1r[tc];
            f32x4 acc = {bv, bv, bv, bv};
            #pragma unroll
            for (int ks = 0; ks < 8; ++ks) {
                s16x8 b = *(const s16x8*)&sB1[col * 264 + ks * 32 + g4 * 8];
                acc = __builtin_amdgcn_mfma_f32_16x16x32_bf16(a[ks], b, acc, 0, 0, 0);
            }
            #pragma unroll
            for (int j = 0; j < 4; ++j)
                st[(g4 * 4 + j) * 136 + col] = f2bf(fmaxf(acc[j], 0.f));
        }
        WFENCE();
        s16x8 a2[4];
        #pragma unroll
        for (int ks = 0; ks < 4; ++ks)
            a2[ks] = *(const s16x8*)&st[r16 * 136 + ks * 32 + g4 * 8];
        WFENCE();
        // GEMM2: out = t @ uw2 + ub2 (f32 coalesced stores)
        #pragma unroll
        for (int tc = 0; tc < 8; ++tc) {
            int col = tc * 16 + r16;
            float bv = ub2r[tc];
            f32x4 acc = {bv, bv, bv, bv};
            #pragma unroll
            for (int ks = 0; ks < 4; ++ks) {
                s16x8 b = *(const s16x8*)&sB2[col * 136 + ks * 32 + g4 * 8];
                acc = __builtin_amdgcn_mfma_f32_16x16x32_bf16(a2[ks], b, acc, 0, 0, 0);
            }
            #pragma unroll
            for (int j = 0; j < 4; ++j)
                out[(size_t)(r0 + g4 * 4 + j) * HD + col] = acc[j];
        }
    }
}

// ---------------------------------------------------------------------------
extern "C" void kernel_launch(void* const* d_in, const int* in_sizes, int n_in,
                              void* d_out, int out_size, void* d_ws, size_t ws_size,
                              hipStream_t stream)
{
    const float* x   = (const float*)d_in[0];
    const float* pos = (const float*)d_in[1];
    const int*   ei  = (const int*)d_in[2];
    const float* pw1 = (const float*)d_in[3];
    const float* pb1 = (const float*)d_in[4];
    const float* pw2 = (const float*)d_in[5];
    const float* pb2 = (const float*)d_in[6];
    const float* mw1 = (const float*)d_in[7];
    const float* mb1 = (const float*)d_in[8];
    const float* mw2 = (const float*)d_in[9];
    const float* mb2 = (const float*)d_in[10];
    const float* uw1 = (const float*)d_in[11];
    const float* ub1 = (const float*)d_in[12];
    const float* uw2 = (const float*)d_in[13];
    const float* ub2 = (const float*)d_in[14];
    float* out = (float*)d_out;

    char* ws = (char*)d_ws;
    float*          aggH   = (float*)(ws);                      // 25,600,000 B
    unsigned short* xa     = (unsigned short*)(ws + 25600000);  // 12,800,000 B
    unsigned short* xb     = (unsigned short*)(ws + 38400000);  // 12,800,000 B
    float*          Wpc    = (float*)(ws + 51200000);           // 16,384 B
    float*          bcv    = (float*)(ws + 51216384);           // 512 B
    int*            cnt    = (int*)(ws + 51216896);             // 200,704 B
    int*            cursor = (int*)(ws + 51417600);             // 200,704 B
    int*            bsum   = (int*)(ws + 51618304);             // 256 B
    int2*           sRC    = (int2*)(ws + 51618560);            // 6,400,000 B

    unsigned short* agg2 = xa;  // xa dead after edge_kernel

    hipMemsetAsync(aggH, 0, (size_t)NN * HD * sizeof(float), stream);
    hipMemsetAsync(cnt, 0, NN * sizeof(int), stream);
    prep_kernel<<<1, 256, 0, stream>>>(pw2, pb2, mw1, mb1, Wpc, bcv);
    hist_kernel<<<(NE / 2 + 255) / 256, 256, 0, stream>>>(ei, cnt);
    scan1_kernel<<<SCAN_BLOCKS, 256, 0, stream>>>(cnt, cursor, bsum);
    scan2_kernel<<<1, 64, 0, stream>>>(bsum);
    scan3_kernel<<<SCAN_BLOCKS, 256, 0, stream>>>(cursor, bsum);
    scatter_kernel<<<(NE / 2 + 255) / 256, 256, 0, stream>>>(ei, cursor, sRC);
    node_pre_kernel<<<512, 256, 0, stream>>>(x, mw1, bcv, xa, xb);
    edge_kernel<<<768, 256, 0, stream>>>(pos, sRC, pw1, pb1, xa, xb, Wpc, aggH);
    aggmm_kernel<<<512, 256, 0, stream>>>(aggH, cnt, mw2, mb2, agg2);
    upd_kernel<<<256, 512, 0, stream>>>(x, agg2, uw1, ub1, uw2, ub2, out);
}